// Round 13
// baseline (2979.528 us; speedup 1.0000x reference)
//
#include <hip/hip_runtime.h>
#include <hip/hip_bf16.h>

typedef __attribute__((ext_vector_type(8))) short short8;
typedef __attribute__((ext_vector_type(4))) short shortv4;
typedef __attribute__((ext_vector_type(4))) float f32x4;

static constexpr int VOC = 50257;
// per-layer transposed-weight region layout (bf16 elements)
static constexpr size_t QKV_T_OFF = 0;
static constexpr size_t AP_T_OFF  = 1769472;            // 2304*768
static constexpr size_t FC_T_OFF  = 2359296;            // + 768*768
static constexpr size_t MP_T_OFF  = 4718592;            // + 3072*768
static constexpr size_t LSTR      = 7077888;            // + 768*3072

__device__ inline unsigned short f2bf(float f){
  unsigned u = __float_as_uint(f);
  unsigned r = (u + 0x7fffu + ((u >> 16) & 1u)) >> 16;
  return (unsigned short)r;
}

// ---------------- embedding ----------------
__global__ __launch_bounds__(192) void embed_kernel(const int* __restrict__ idx,
    const float* __restrict__ wte, const float* __restrict__ wpe, float* __restrict__ x){
  int row = blockIdx.x;              // b*1024+t
  int t = row & 1023;
  int id = idx[row];
  const float* w = wte + (size_t)id * 768;
  const float* p = wpe + (size_t)t * 768;
  float* o = x + (size_t)row * 768;
  int c = threadIdx.x * 4;
  float4 a = *(const float4*)(w + c);
  float4 b = *(const float4*)(p + c);
  float4 r; r.x = a.x + b.x; r.y = a.y + b.y; r.z = a.z + b.z; r.w = a.w + b.w;
  *(float4*)(o + c) = r;
}

// ---------------- layernorm: 1 wave per row, float4 loads, shfl-only ----------------
__global__ __launch_bounds__(256) void ln_kernel(const float* __restrict__ x,
    const float* __restrict__ w, const float* __restrict__ b,
    unsigned short* __restrict__ out){
  int row  = blockIdx.x * 4 + (threadIdx.x >> 6);
  int lane = threadIdx.x & 63;
  const float* xr = x + (size_t)row * 768;
  float4 v0 = *(const float4*)(xr + lane * 4);
  float4 v1 = *(const float4*)(xr + 256 + lane * 4);
  float4 v2 = *(const float4*)(xr + 512 + lane * 4);
  float s = (v0.x + v0.y + v0.z + v0.w) + (v1.x + v1.y + v1.z + v1.w)
          + (v2.x + v2.y + v2.z + v2.w);
  #pragma unroll
  for (int o = 32; o; o >>= 1) s += __shfl_xor(s, o, 64);
  float mu = s * (1.f / 768.f);
  float q =
    (v0.x-mu)*(v0.x-mu) + (v0.y-mu)*(v0.y-mu) + (v0.z-mu)*(v0.z-mu) + (v0.w-mu)*(v0.w-mu) +
    (v1.x-mu)*(v1.x-mu) + (v1.y-mu)*(v1.y-mu) + (v1.z-mu)*(v1.z-mu) + (v1.w-mu)*(v1.w-mu) +
    (v2.x-mu)*(v2.x-mu) + (v2.y-mu)*(v2.y-mu) + (v2.z-mu)*(v2.z-mu) + (v2.w-mu)*(v2.w-mu);
  #pragma unroll
  for (int o = 32; o; o >>= 1) q += __shfl_xor(q, o, 64);
  float rstd = rsqrtf(q * (1.f / 768.f) + 1e-5f);
  unsigned short* orow = out + (size_t)row * 768;
  #pragma unroll
  for (int seg = 0; seg < 3; seg++){
    float4 v = seg == 0 ? v0 : (seg == 1 ? v1 : v2);
    float4 wv = *(const float4*)(w + seg * 256 + lane * 4);
    float4 bv = *(const float4*)(b + seg * 256 + lane * 4);
    shortv4 o4;
    o4[0] = (short)f2bf((v.x - mu) * rstd * wv.x + bv.x);
    o4[1] = (short)f2bf((v.y - mu) * rstd * wv.y + bv.y);
    o4[2] = (short)f2bf((v.z - mu) * rstd * wv.z + bv.z);
    o4[3] = (short)f2bf((v.w - mu) * rstd * wv.w + bv.w);
    *(shortv4*)(orow + seg * 256 + lane * 4) = o4;
  }
}

// ---------------- batched transpose+cvt of all 4 weight families ----------------
__global__ void transpose_all(const float* __restrict__ qkvw, const float* __restrict__ apw,
    const float* __restrict__ fcw, const float* __restrict__ mpw,
    unsigned short* __restrict__ dst){
  __shared__ float t[32][33];
  int l = blockIdx.y;
  int tile = blockIdx.x;
  const float* W; unsigned short* D; int K, N, ntx, tl;
  if (tile < 1728){      W = qkvw + (size_t)l * 768 * 2304; D = dst + (size_t)l * LSTR + QKV_T_OFF; K = 768;  N = 2304; ntx = 72; tl = tile; }
  else if (tile < 2304){ W = apw  + (size_t)l * 768 * 768;  D = dst + (size_t)l * LSTR + AP_T_OFF;  K = 768;  N = 768;  ntx = 24; tl = tile - 1728; }
  else if (tile < 4608){ W = fcw  + (size_t)l * 768 * 3072; D = dst + (size_t)l * LSTR + FC_T_OFF;  K = 768;  N = 3072; ntx = 96; tl = tile - 2304; }
  else {                 W = mpw  + (size_t)l * 3072 * 768; D = dst + (size_t)l * LSTR + MP_T_OFF;  K = 3072; N = 768;  ntx = 24; tl = tile - 4608; }
  int n0 = (tl % ntx) * 32, k0 = (tl / ntx) * 32;
  int tx = threadIdx.x, ty = threadIdx.y; // (32,8)
  #pragma unroll
  for (int i = 0; i < 4; i++)
    t[ty + i * 8][tx] = W[(size_t)(k0 + ty + i * 8) * N + n0 + tx];
  __syncthreads();
  #pragma unroll
  for (int i = 0; i < 4; i++)
    D[(size_t)(n0 + ty + i * 8) * K + k0 + tx] = f2bf(t[tx][ty + i * 8]);
}

// ---------------- elementwise f32 -> bf16 ----------------
__global__ void cvt_bf16_kernel(const float* __restrict__ src, unsigned short* __restrict__ dst, int n4){
  int i = blockIdx.x * blockDim.x + threadIdx.x;
  int stride = gridDim.x * blockDim.x;
  for (; i < n4; i += stride){
    float4 v = *(const float4*)(src + (size_t)i * 4);
    size_t o = (size_t)i * 4;
    dst[o + 0] = f2bf(v.x); dst[o + 1] = f2bf(v.y);
    dst[o + 2] = f2bf(v.z); dst[o + 3] = f2bf(v.w);
  }
}

// ======== 256x128 main-loop macro: BK=64, 8 waves (4Mx2N), 512 thr ========
#define GEMM256_MAIN_LOOP(CLAMP_B)                                                  \
  f32x4 acc[4][4];                                                                  \
  _Pragma("unroll")                                                                 \
  for (int m = 0; m < 4; m++)                                                       \
    _Pragma("unroll")                                                               \
    for (int n = 0; n < 4; n++)                                                     \
      acc[m][n] = (f32x4){0.f, 0.f, 0.f, 0.f};                                      \
  for (int k0 = 0; k0 < K; k0 += 64){                                               \
    _Pragma("unroll")                                                               \
    for (int i = 0; i < 4; i++){                                                    \
      int p = (i * 8 + wid) * 64 + lane;                                            \
      int r = p >> 3, c = p & 7;                                                    \
      int cs = c ^ (r & 7);                                                         \
      const unsigned short* g = A + (size_t)(brow + r) * K + k0 + cs * 8;           \
      __builtin_amdgcn_global_load_lds(                                             \
        (const __attribute__((address_space(1))) unsigned int*)g,                   \
        (__attribute__((address_space(3))) unsigned int*)(tA + (size_t)(i * 8 + wid) * 64 * 8), \
        16, 0, 0);                                                                  \
    }                                                                               \
    _Pragma("unroll")                                                               \
    for (int i = 0; i < 2; i++){                                                    \
      int p = (i * 8 + wid) * 64 + lane;                                            \
      int r = p >> 3, c = p & 7;                                                    \
      int cs = c ^ (r & 7);                                                         \
      int rc = CLAMP_B;                                                             \
      const unsigned short* g = Bm + (size_t)(bcol + rc) * K + k0 + cs * 8;         \
      __builtin_amdgcn_global_load_lds(                                             \
        (const __attribute__((address_space(1))) unsigned int*)g,                   \
        (__attribute__((address_space(3))) unsigned int*)(tB + (size_t)(i * 8 + wid) * 64 * 8), \
        16, 0, 0);                                                                  \
    }                                                                               \
    __syncthreads();                                                                \
    _Pragma("unroll")                                                               \
    for (int kk = 0; kk < 2; kk++){                                                 \
      short8 av[4], bv[4];                                                          \
      _Pragma("unroll")                                                             \
      for (int m = 0; m < 4; m++){                                                  \
        int R = wr * 64 + m * 16 + lr;                                              \
        int c = kk * 4 + lk;                                                        \
        av[m] = *(const short8*)&tA[R * 64 + ((c ^ (R & 7)) << 3)];                 \
      }                                                                             \
      _Pragma("unroll")                                                             \
      for (int n = 0; n < 4; n++){                                                  \
        int R = wc * 64 + n * 16 + lr;                                              \
        int c = kk * 4 + lk;                                                        \
        bv[n] = *(const short8*)&tB[R * 64 + ((c ^ (R & 7)) << 3)];                 \
      }                                                                             \
      _Pragma("unroll")                                                             \
      for (int m = 0; m < 4; m++)                                                   \
        _Pragma("unroll")                                                           \
        for (int n = 0; n < 4; n++)                                                 \
          acc[m][n] = __builtin_amdgcn_mfma_f32_16x16x32_bf16(av[m], bv[n], acc[m][n], 0, 0, 0); \
    }                                                                               \
    __syncthreads();                                                                \
  }

// ---------------- fc GEMM: 256x128, bias+GELU(fast tanh) -> bf16 ----------------
__global__ __launch_bounds__(512) void gemm_fc256(
    const unsigned short* __restrict__ A,
    const unsigned short* __restrict__ Bm,
    const float* __restrict__ bias,
    unsigned short* __restrict__ outB,
    int M, int N, int K)
{
  __shared__ unsigned short tA[16384];
  __shared__ unsigned short tB[8192];
  const int lane = threadIdx.x & 63;
  const int wid  = threadIdx.x >> 6;
  const int wr = wid >> 1, wc = wid & 1;
  const int lr = lane & 15, lk = lane >> 4;
  const int nbx = gridDim.x, nby = gridDim.y;
  const int nwg = nbx * nby;
  const int lin = blockIdx.y * nbx + blockIdx.x;
  const int qq = nwg >> 3, rr8 = nwg & 7;
  const int xcd = lin & 7, loc = lin >> 3;
  const int wg = (xcd < rr8 ? xcd * (qq + 1) : rr8 * (qq + 1) + (xcd - rr8) * qq) + loc;
  const int mblk = wg / nbx, nblk = wg % nbx;
  const int brow = mblk * 256;
  const int bcol = nblk * 128;

  GEMM256_MAIN_LOOP(r)

  #pragma unroll
  for (int m = 0; m < 4; m++){
    #pragma unroll
    for (int n = 0; n < 4; n++){
      int col = bcol + wc * 64 + n * 16 + lr;
      float bco = bias[col];
      #pragma unroll
      for (int j = 0; j < 4; j++){
        int row = brow + wr * 64 + m * 16 + lk * 4 + j;
        float v = acc[m][n][j] + bco;
        float z = 0.79788456080286536f * (v + 0.044715f * v * v * v);
        float az = fabsf(z);
        float e = __expf(-2.f * az);
        float t = (1.f - e) / (1.f + e);
        t = z < 0.f ? -t : t;
        v = 0.5f * v * (1.f + t);
        outB[(size_t)row * N + col] = f2bf(v);
      }
    }
  }
}

// ---------------- QKV GEMM 256x128 with fused repack ----------------
__global__ __launch_bounds__(512) void gemm_qkv256(
    const unsigned short* __restrict__ A,
    const unsigned short* __restrict__ Bm,
    const float* __restrict__ bias,
    unsigned short* __restrict__ Qb,   // [BH,1024,64]
    unsigned short* __restrict__ Kb,
    unsigned short* __restrict__ VT,   // [BH,64,1024]
    int M, int N, int K)
{
  __shared__ unsigned short tA[16384];
  __shared__ unsigned short tB[8192];
  const int lane = threadIdx.x & 63;
  const int wid  = threadIdx.x >> 6;
  const int wr = wid >> 1, wc = wid & 1;
  const int lr = lane & 15, lk = lane >> 4;
  const int nbx = gridDim.x, nby = gridDim.y;
  const int nwg = nbx * nby;
  const int lin = blockIdx.y * nbx + blockIdx.x;
  const int qq = nwg >> 3, rr8 = nwg & 7;
  const int xcd = lin & 7, loc = lin >> 3;
  const int wg = (xcd < rr8 ? xcd * (qq + 1) : rr8 * (qq + 1) + (xcd - rr8) * qq) + loc;
  const int mblk = wg / nbx, nblk = wg % nbx;
  const int brow = mblk * 256;         // never spans a 1024-row batch boundary
  const int bcol = nblk * 128;

  GEMM256_MAIN_LOOP(r)

  const int b = brow >> 10, tstart = brow & 1023;
  if (bcol < 1536){
    // Q or K scatter: [BH, t, 64] bf16
    #pragma unroll
    for (int m = 0; m < 4; m++)
      #pragma unroll
      for (int n = 0; n < 4; n++){
        int col = bcol + wc * 64 + n * 16 + lr;
        float bco = bias[col];
        int isK = col >= 768;
        int h = (isK ? col - 768 : col) >> 6;
        unsigned short* dstp = isK ? Kb : Qb;
        #pragma unroll
        for (int j = 0; j < 4; j++){
          int t = tstart + wr * 64 + m * 16 + lk * 4 + j;
          dstp[(((size_t)b * 12 + h) * 1024 + t) * 64 + (col & 63)] =
              f2bf(acc[m][n][j] + bco);
        }
      }
  } else {
    // V: transpose 256x128 in four 64-row passes through 64x136 LDS (in tA)
    unsigned short* sh = tA;   // 8704 shorts used
    const int h0 = (bcol - 1536) >> 6;
    #pragma unroll
    for (int half = 0; half < 4; half++){
      __syncthreads();
      if (wr == half){
        #pragma unroll
        for (int m = 0; m < 4; m++)
          #pragma unroll
          for (int n = 0; n < 4; n++){
            int lcol = wc * 64 + n * 16 + lr;
            float bco = bias[bcol + lcol];
            #pragma unroll
            for (int j = 0; j < 4; j++)
              sh[(m * 16 + lk * 4 + j) * 136 + lcol] = f2bf(acc[m][n][j] + bco);
          }
      }
      __syncthreads();
      int c_local = threadIdx.x & 127, tpart = threadIdx.x >> 7; // 0..3 (16 rows each)
      int h = h0 + (c_local >> 6);
      int d = c_local & 63;
      unsigned short* vrow = VT + (((size_t)b * 12 + h) * 64 + d) * 1024
                           + tstart + half * 64 + tpart * 16;
      #pragma unroll
      for (int i = 0; i < 2; i++){
        short8 pk;
        #pragma unroll
        for (int s2 = 0; s2 < 8; s2++)
          pk[s2] = (short)sh[(tpart * 16 + i * 8 + s2) * 136 + c_local];
        *(short8*)&vrow[i * 8] = pk;
      }
    }
  }
}

// ---------------- small-N GEMM: BM=128 x BN=64, 4 waves (2Mx2N, wave 64x32) ----------------
__global__ __launch_bounds__(256) void gemm_n64(
    const unsigned short* __restrict__ A,
    const unsigned short* __restrict__ Bm,
    const float* __restrict__ bias,
    const float* __restrict__ resid,
    float* __restrict__ outF,
    int M, int N, int K)
{
  __shared__ unsigned short tA[8192];   // 128 x 64
  __shared__ unsigned short tB[4096];   // 64 x 64
  const int lane = threadIdx.x & 63;
  const int wid  = threadIdx.x >> 6;
  const int wr = wid >> 1, wc = wid & 1;
  const int lr = lane & 15, lk = lane >> 4;
  const int nbx = gridDim.x, nby = gridDim.y;   // nbx = N/64
  const int nwg = nbx * nby;
  const int lin = blockIdx.y * nbx + blockIdx.x;
  const int qq = nwg >> 3, rr8 = nwg & 7;
  const int xcd = lin & 7, loc = lin >> 3;
  const int wg = (xcd < rr8 ? xcd * (qq + 1) : rr8 * (qq + 1) + (xcd - rr8) * qq) + loc;
  const int mblk = wg / nbx, nblk = wg % nbx;
  const int brow = mblk * 128;
  const int bcol = nblk * 64;

  f32x4 acc[4][2];
  #pragma unroll
  for (int m = 0; m < 4; m++)
    #pragma unroll
    for (int n = 0; n < 2; n++)
      acc[m][n] = (f32x4){0.f, 0.f, 0.f, 0.f};

  for (int k0 = 0; k0 < K; k0 += 64){
    #pragma unroll
    for (int i = 0; i < 4; i++){
      int p = (i * 4 + wid) * 64 + lane;      // A: 1024 chunks
      int r = p >> 3, c = p & 7;
      int cs = c ^ (r & 7);
      const unsigned short* g = A + (size_t)(brow + r) * K + k0 + cs * 8;
      __builtin_amdgcn_global_load_lds(
        (const __attribute__((address_space(1))) unsigned int*)g,
        (__attribute__((address_space(3))) unsigned int*)(tA + (size_t)(i * 4 + wid) * 64 * 8),
        16, 0, 0);
    }
    #pragma unroll
    for (int i = 0; i < 2; i++){
      int p = (i * 4 + wid) * 64 + lane;      // B: 512 chunks (64 rows)
      int r = p >> 3, c = p & 7;
      int cs = c ^ (r & 7);
      const unsigned short* g = Bm + (size_t)(bcol + r) * K + k0 + cs * 8;
      __builtin_amdgcn_global_load_lds(
        (const __attribute__((address_space(1))) unsigned int*)g,
        (__attribute__((address_space(3))) unsigned int*)(tB + (size_t)(i * 4 + wid) * 64 * 8),
        16, 0, 0);
    }
    __syncthreads();
    #pragma unroll
    for (int kk = 0; kk < 2; kk++){
      short8 av[4], bv[2];
      #pragma unroll
      for (int m = 0; m < 4; m++){
        int R = wr * 64 + m * 16 + lr;
        int c = kk * 4 + lk;
        av[m] = *(const short8*)&tA[R * 64 + ((c ^ (R & 7)) << 3)];
      }
      #pragma unroll
      for (int n = 0; n < 2; n++){
        int R = wc * 32 + n * 16 + lr;
        int c = kk * 4 + lk;
        bv[n] = *(const short8*)&tB[R * 64 + ((c ^ (R & 7)) << 3)];
      }
      #pragma unroll
      for (int m = 0; m < 4; m++)
        #pragma unroll
        for (int n = 0; n < 2; n++)
          acc[m][n] = __builtin_amdgcn_mfma_f32_16x16x32_bf16(av[m], bv[n], acc[m][n], 0, 0, 0);
    }
    __syncthreads();
  }

  #pragma unroll
  for (int m = 0; m < 4; m++){
    #pragma unroll
    for (int n = 0; n < 2; n++){
      int col = bcol + wc * 32 + n * 16 + lr;
      float bco = bias[col];
      #pragma unroll
      for (int j = 0; j < 4; j++){
        int row = brow + wr * 64 + m * 16 + lk * 4 + j;
        float v = acc[m][n][j] + bco + resid[(size_t)row * N + col];
        outF[(size_t)row * N + col] = v;
      }
    }
  }
}

// ---------------- tiny-tile GEMM: BM=64 x BN=64, 4 waves (2Mx2N, wave 32x32) ----------------
__global__ __launch_bounds__(256) void gemm_n64s(
    const unsigned short* __restrict__ A,
    const unsigned short* __restrict__ Bm,
    const float* __restrict__ bias,
    const float* __restrict__ resid,
    float* __restrict__ outF,
    int M, int N, int K)
{
  __shared__ unsigned short tA[4096];   // 64 x 64
  __shared__ unsigned short tB[4096];   // 64 x 64
  const int lane = threadIdx.x & 63;
  const int wid  = threadIdx.x >> 6;
  const int wr = wid >> 1, wc = wid & 1;
  const int lr = lane & 15, lk = lane >> 4;
  const int nbx = gridDim.x, nby = gridDim.y;   // nbx = N/64, nby = M/64
  const int nwg = nbx * nby;
  const int lin = blockIdx.y * nbx + blockIdx.x;
  const int qq = nwg >> 3, rr8 = nwg & 7;
  const int xcd = lin & 7, loc = lin >> 3;
  const int wg = (xcd < rr8 ? xcd * (qq + 1) : rr8 * (qq + 1) + (xcd - rr8) * qq) + loc;
  const int mblk = wg / nbx, nblk = wg % nbx;
  const int brow = mblk * 64;
  const int bcol = nblk * 64;

  f32x4 acc[2][2];
  #pragma unroll
  for (int m = 0; m < 2; m++)
    #pragma unroll
    for (int n = 0; n < 2; n++)
      acc[m][n] = (f32x4){0.f, 0.f, 0.f, 0.f};

  for (int k0 = 0; k0 < K; k0 += 64){
    #pragma unroll
    for (int i = 0; i < 2; i++){
      int p = (i * 4 + wid) * 64 + lane;      // 512 chunks each
      int r = p >> 3, c = p & 7;
      int cs = c ^ (r & 7);
      const unsigned short* ga = A + (size_t)(brow + r) * K + k0 + cs * 8;
      __builtin_amdgcn_global_load_lds(
        (const __attribute__((address_space(1))) unsigned int*)ga,
        (__attribute__((address_space(3))) unsigned int*)(tA + (size_t)(i * 4 + wid) * 64 * 8),
        16, 0, 0);
      const unsigned short* gb = Bm + (size_t)(bcol + r) * K + k0 + cs * 8;
      __builtin_amdgcn_global_load_lds(
        (const __attribute__((address_space(1))) unsigned int*)gb,
        (__attribute__((address_space(3))) unsigned int*)(tB + (size_t)(i * 4 + wid) * 64 * 8),
        16, 0, 0);
    }
    __syncthreads();
    #pragma unroll
    for (int kk = 0; kk < 2; kk++){
      short8 av[2], bv[2];
      #pragma unroll
      for (int m = 0; m < 2; m++){
        int R = wr * 32 + m * 16 + lr;
        int c = kk * 4 + lk;
        av[m] = *(const short8*)&tA[R * 64 + ((c ^ (R & 7)) << 3)];
      }
      #pragma unroll
      for (int n = 0; n < 2; n++){
        int R = wc * 32 + n * 16 + lr;
        int c = kk * 4 + lk;
        bv[n] = *(const short8*)&tB[R * 64 + ((c ^ (R & 7)) << 3)];
      }
      #pragma unroll
      for (int m = 0; m < 2; m++)
        #pragma unroll
        for (int n = 0; n < 2; n++)
          acc[m][n] = __builtin_amdgcn_mfma_f32_16x16x32_bf16(av[m], bv[n], acc[m][n], 0, 0, 0);
    }
    __syncthreads();
  }

  #pragma unroll
  for (int m = 0; m < 2; m++){
    #pragma unroll
    for (int n = 0; n < 2; n++){
      int col = bcol + wc * 32 + n * 16 + lr;
      float bco = bias[col];
      #pragma unroll
      for (int j = 0; j < 4; j++){
        int row = brow + wr * 32 + m * 16 + lk * 4 + j;
        float v = acc[m][n][j] + bco + resid[(size_t)row * N + col];
        outF[(size_t)row * N + col] = v;
      }
    }
  }
}

// ---------------- lm_head GEMM: BM=256 x BN=128, 512 threads (8 waves 4Mx2N) ----------------
__global__ __launch_bounds__(512) void gemm_head(
    const unsigned short* __restrict__ A,
    const unsigned short* __restrict__ Bm,
    float* __restrict__ outF,
    float2* __restrict__ lossPart,
    int M, int N, int K, int nPart)
{
  __shared__ unsigned short tA[16384];   // 256 x 64
  __shared__ unsigned short tB[8192];    // 128 x 64
  const int lane = threadIdx.x & 63;
  const int wid  = threadIdx.x >> 6;     // 0..7
  const int wr = wid >> 1, wc = wid & 1; // wr 0..3, wc 0..1
  const int lr = lane & 15, lk = lane >> 4;
  const int nblk = blockIdx.x, mblk = blockIdx.y;  // plain N-fastest
  const int brow = mblk * 256;
  const int bcol = nblk * 128;
  const int nValid = N - bcol;

  GEMM256_MAIN_LOOP(r < nValid ? r : (nValid - 1))

  #pragma unroll
  for (int m = 0; m < 4; m++){
    #pragma unroll
    for (int n = 0; n < 4; n++){
      int col = bcol + wc * 64 + n * 16 + lr;
      if (col < N){
        #pragma unroll
        for (int j = 0; j < 4; j++){
          int row = brow + wr * 64 + m * 16 + lk * 4 + j;
          outF[(size_t)row * N + col] = acc[m][n][j];
        }
      }
    }
  }

  // fused loss partials: per row (max, sum_exp) over this 128-col slice
  float* mred = (float*)tA;          // 512+512 floats, safe after final barrier
  float* sred = mred + 512;
  #pragma unroll
  for (int m = 0; m < 4; m++){
    #pragma unroll
    for (int j = 0; j < 4; j++){
      float vv[4];
      float mx = -3.4e38f;
      #pragma unroll
      for (int n = 0; n < 4; n++){
        int col = bcol + wc * 64 + n * 16 + lr;
        vv[n] = (col < N) ? acc[m][n][j] : -3.4e38f;
        mx = fmaxf(mx, vv[n]);
      }
      #pragma unroll
      for (int msk = 1; msk < 16; msk <<= 1)
        mx = fmaxf(mx, __shfl_xor(mx, msk, 64));
      float sm = 0.f;
      #pragma unroll
      for (int n = 0; n < 4; n++){
        int col = bcol + wc * 64 + n * 16 + lr;
        if (col < N) sm += __expf(vv[n] - mx);
      }
      #pragma unroll
      for (int msk = 1; msk < 16; msk <<= 1)
        sm += __shfl_xor(sm, msk, 64);
      if (lr == 0){
        int rid = (wr * 2 + wc) * 64 + m * 16 + lk * 4 + j;   // [0,512)
        mred[rid] = mx; sred[rid] = sm;
      }
    }
  }
  __syncthreads();
  if (threadIdx.x < 256){
    int wrq = threadIdx.x >> 6, rowi = threadIdx.x & 63;       // wrq 0..3
    float m0 = mred[(wrq * 2 + 0) * 64 + rowi];
    float m1 = mred[(wrq * 2 + 1) * 64 + rowi];
    float s0 = sred[(wrq * 2 + 0) * 64 + rowi];
    float s1 = sred[(wrq * 2 + 1) * 64 + rowi];
    float Mv = fmaxf(m0, m1);
    float Sv = (s0 > 0.f ? s0 * __expf(m0 - Mv) : 0.f)
             + (s1 > 0.f ? s1 * __expf(m1 - Mv) : 0.f);
    int grow = brow + wrq * 64 + rowi;
    lossPart[(size_t)grow * nPart + nblk] = make_float2(Mv, Sv);
  }
}

// ---------------- MFMA flash attention: QBLK=128, 8 waves ----------------
// Each wave owns 16 q-rows; one K/V staging round serves 128 q-rows
// (staging bytes per q-row halved vs QBLK=64). s_setprio around MFMA (T5).
__global__ __launch_bounds__(512) void attn_mfma(
    const unsigned short* __restrict__ Qb,   // [BH,1024,64]
    const unsigned short* __restrict__ Kb,   // [BH,1024,64]
    const unsigned short* __restrict__ VT,   // [BH,64,1024]
    unsigned short* __restrict__ y)          // [B*T,768]
{
  __shared__ unsigned short Kl[64 * 64];
  __shared__ unsigned short Vl[64 * 64];
  __shared__ unsigned short Pl[8][16 * 72];
  const int xq = blockIdx.x;                 // 0..7
  const int qt = (xq & 1) ? (xq >> 1) : (7 - (xq >> 1)); // interleave heavy/light
  const int h = blockIdx.y, b = blockIdx.z;
  const size_t bh = (size_t)(b * 12 + h);
  const int lane = threadIdx.x & 63;
  const int w = threadIdx.x >> 6;            // 0..7
  const int lr = lane & 15, lk = lane >> 4;
  const int rowBase = qt * 128 + w * 16;     // this wave's first q-row

  short8 aq[2];
  {
    const unsigned short* qrow = Qb + ((bh * 1024) + rowBase + lr) * 64;
    aq[0] = *(const short8*)&qrow[lk * 8];
    aq[1] = *(const short8*)&qrow[32 + lk * 8];
  }

  f32x4 o[4];
  #pragma unroll
  for (int n = 0; n < 4; n++) o[n] = (f32x4){0.f, 0.f, 0.f, 0.f};
  float mold[4] = {-1e30f, -1e30f, -1e30f, -1e30f};
  float lsum[4] = {0.f, 0.f, 0.f, 0.f};

  const int ktMax = 2 * qt + 1;
  for (int kt = 0; kt <= ktMax; kt++){
    { // stage K and VT tiles: 512 chunks each, 1 per thread, swizzled
      int p = w * 64 + lane;
      int r = p >> 3, c = p & 7;
      int cs = c ^ (r & 7);
      const unsigned short* gk = Kb + (bh * 1024 + (size_t)kt * 64 + r) * 64 + cs * 8;
      __builtin_amdgcn_global_load_lds(
        (const __attribute__((address_space(1))) unsigned int*)gk,
        (__attribute__((address_space(3))) unsigned int*)(Kl + (size_t)w * 512),
        16, 0, 0);
      const unsigned short* gv = VT + (bh * 64 + r) * 1024 + (size_t)kt * 64 + cs * 8;
      __builtin_amdgcn_global_load_lds(
        (const __attribute__((address_space(1))) unsigned int*)gv,
        (__attribute__((address_space(3))) unsigned int*)(Vl + (size_t)w * 512),
        16, 0, 0);
    }
    __syncthreads();

    f32x4 s[4];
    #pragma unroll
    for (int n = 0; n < 4; n++) s[n] = (f32x4){0.f, 0.f, 0.f, 0.f};
    __builtin_amdgcn_s_setprio(1);
    #pragma unroll
    for (int ck = 0; ck < 2; ck++){
      #pragma unroll
      for (int n = 0; n < 4; n++){
        int R = n * 16 + lr, c = ck * 4 + lk;
        short8 bv = *(const short8*)&Kl[R * 64 + ((c ^ (R & 7)) << 3)];
        s[n] = __builtin_amdgcn_mfma_f32_16x16x32_bf16(aq[ck], bv, s[n], 0, 0, 0);
      }
    }
    __builtin_amdgcn_s_setprio(0);
    if (kt >= 2 * qt){
      // diagonal region: mask key > row
      #pragma unroll
      for (int n = 0; n < 4; n++)
        #pragma unroll
        for (int j = 0; j < 4; j++){
          float v = s[n][j] * 0.125f;
          if (kt * 64 + n * 16 + lr > rowBase + lk * 4 + j) v = -1e30f;
          s[n][j] = v;
        }
    } else {
      #pragma unroll
      for (int n = 0; n < 4; n++)
        #pragma unroll
        for (int j = 0; j < 4; j++)
          s[n][j] *= 0.125f;
    }
    float mt[4];
    #pragma unroll
    for (int j = 0; j < 4; j++)
      mt[j] = fmaxf(fmaxf(s[0][j], s[1][j]), fmaxf(s[2][j], s[3][j]));
    #pragma unroll
    for (int msk = 1; msk < 16; msk <<= 1)
      #pragma unroll
      for (int j = 0; j < 4; j++)
        mt[j] = fmaxf(mt[j], __shfl_xor(mt[j], msk, 64));
    #pragma unroll
    for (int j = 0; j < 4; j++){
      float mn = fmaxf(mold[j], mt[j]);
      float a = __expf(mold[j] - mn);
      mold[j] = mn;
      lsum[j] *= a;
      #pragma unroll
      for (int n = 0; n < 4; n++){
        float p = __expf(s[n][j] - mn);
        s[n][j] = p;
        lsum[j] += p;
      }
      #pragma unroll
      for (int n2 = 0; n2 < 4; n2++) o[n2][j] *= a;
    }
    #pragma unroll
    for (int n = 0; n < 4; n++)
      #pragma unroll
      for (int j = 0; j < 4; j++)
        Pl[w][(lk * 4 + j) * 72 + n * 16 + lr] = f2bf(s[n][j]);
    __syncthreads();
    __builtin_amdgcn_s_setprio(1);
    #pragma unroll
    for (int ck = 0; ck < 2; ck++){
      short8 pa = *(const short8*)&Pl[w][lr * 72 + ck * 32 + lk * 8];
      #pragma unroll
      for (int n2 = 0; n2 < 4; n2++){
        int R = n2 * 16 + lr, c = ck * 4 + lk;
        short8 vv = *(const short8*)&Vl[R * 64 + ((c ^ (R & 7)) << 3)];
        o[n2] = __builtin_amdgcn_mfma_f32_16x16x32_bf16(pa, vv, o[n2], 0, 0, 0);
      }
    }
    __builtin_amdgcn_s_setprio(0);
    __syncthreads();
  }

  #pragma unroll
  for (int msk = 1; msk < 16; msk <<= 1)
    #pragma unroll
    for (int j = 0; j < 4; j++)
      lsum[j] += __shfl_xor(lsum[j], msk, 64);
  float inv[4];
  #pragma unroll
  for (int j = 0; j < 4; j++) inv[j] = 1.f / lsum[j];

  #pragma unroll
  for (int n2 = 0; n2 < 4; n2++)
    #pragma unroll
    for (int j = 0; j < 4; j++){
      size_t row = (size_t)(b * 1024 + rowBase + lk * 4 + j);
      y[row * 768 + h * 64 + n2 * 16 + lr] = f2bf(o[n2][j] * inv[j]);
    }
}

// ---------------- loss: combine per-block partials ----------------
__global__ __launch_bounds__(64) void loss_rows2(const float2* __restrict__ part,
    const float* __restrict__ logits, const int* __restrict__ targets,
    float* __restrict__ nll, int nPart){
  int row = blockIdx.x, lane = threadIdx.x;
  float m = -3.4e38f, s = 0.f;
  for (int i = lane; i < nPart; i += 64){
    float2 p = part[(size_t)row * nPart + i];
    if (p.y > 0.f){
      float nm = fmaxf(m, p.x);
      s = s * __expf(m - nm) + p.y * __expf(p.x - nm);
      m = nm;
    }
  }
  #pragma unroll
  for (int o = 32; o; o >>= 1){
    float m2 = __shfl_xor(m, o, 64);
    float s2 = __shfl_xor(s, o, 64);
    float nm = fmaxf(m, m2);
    s = s * __expf(m - nm) + s2 * __expf(m2 - nm);
    m = nm;
  }
  if (lane == 0)
    nll[row] = m + logf(s) - logits[(size_t)row * VOC + targets[row]];
}

__global__ __launch_bounds__(256) void loss_final(const float* __restrict__ nll,
                                                  float* __restrict__ out){
  __shared__ float red[4];
  int tid = threadIdx.x;
  float s = 0.f;
  for (int i = tid; i < 4096; i += 256) s += nll[i];
  #pragma unroll
  for (int o = 32; o; o >>= 1) s += __shfl_xor(s, o, 64);
  if ((tid & 63) == 0) red[tid >> 6] = s;
  __syncthreads();
  if (tid == 0) out[0] = (red[0] + red[1] + red[2] + red[3]) * (1.f / 4096.f);
}

// ---------------- host ----------------
extern "C" void kernel_launch(void* const* d_in, const int* in_sizes, int n_in,
                              void* d_out, int out_size, void* d_ws, size_t ws_size,
                              hipStream_t stream){
  (void)in_sizes; (void)n_in; (void)out_size;
  const int*   idx     = (const int*)d_in[0];
  const int*   targets = (const int*)d_in[1];
  const float* wte     = (const float*)d_in[2];
  const float* wpe     = (const float*)d_in[3];
  const float* ln1w    = (const float*)d_in[4];
  const float* ln1b    = (const float*)d_in[5];
  const float* qkvw    = (const float*)d_in[6];
  const float* qkvb    = (const float*)d_in[7];
  const float* apw     = (const float*)d_in[8];
  const float* apb     = (const float*)d_in[9];
  const float* ln2w    = (const float*)d_in[10];
  const float* ln2b    = (const float*)d_in[11];
  const float* fcw     = (const float*)d_in[12];
  const float* fcb     = (const float*)d_in[13];
  const float* mpw     = (const float*)d_in[14];
  const float* mpb     = (const float*)d_in[15];
  const float* lnfw    = (const float*)d_in[16];
  const float* lnfb    = (const float*)d_in[17];

  char* ws = (char*)d_ws;
  size_t off = 0;
  auto alloc = [&](size_t bytes){
    void* p = ws + off; off += (bytes + 255) & ~(size_t)255; return p;
  };
  float* x               = (float*)alloc((size_t)4096 * 768 * 4);
  unsigned short* hbf    = (unsigned short*)alloc((size_t)4096 * 768 * 2);
  unsigned short* ybf    = (unsigned short*)alloc((size_t)4096 * 768 * 2);
  unsigned short* gbf    = (unsigned short*)alloc((size_t)4096 * 3072 * 2);
  unsigned short* wtebf  = (unsigned short*)alloc((size_t)VOC * 768 * 2);
  unsigned short* qb     = (unsigned short*)alloc((size_t)48 * 1024 * 64 * 2);
  unsigned short* kbf    = (unsigned short*)alloc((size_t)48 * 1024 * 64 * 2);
  unsigned short* vtb    = (unsigned short*)alloc((size_t)48 * 1024 * 64 * 2);
  float2* lossPart       = (float2*)alloc((size_t)4096 * 393 * 8);
  float* nll             = (float*)alloc((size_t)4096 * 4);
  // transposed weights: all 12 layers if ws allows, else per-layer ping buffer
  bool mega = (ws_size - off) >= (12 * LSTR * 2 + 256);
  unsigned short* wTall = (unsigned short*)alloc(mega ? 12 * LSTR * 2 : LSTR * 2);

  float* logits  = (float*)d_out;
  float* lossOut = logits + (size_t)4096 * VOC;

  cvt_bf16_kernel<<<2048, 256, 0, stream>>>(wte, wtebf, (VOC * 768) / 4);
  embed_kernel<<<4096, 192, 0, stream>>>(idx, wte, wpe, x);
  if (mega)
    transpose_all<<<dim3(6912, 12), dim3(32, 8), 0, stream>>>(qkvw, apw, fcw, mpw, wTall);

  for (int l = 0; l < 12; l++){
    unsigned short* wTl = wTall;
    if (mega) wTl = wTall + (size_t)l * LSTR;
    else
      transpose_all<<<dim3(6912, 1), dim3(32, 8), 0, stream>>>(
          qkvw + (size_t)l * 768 * 2304, apw + (size_t)l * 768 * 768,
          fcw + (size_t)l * 768 * 3072, mpw + (size_t)l * 3072 * 768, wTall);

    ln_kernel<<<1024, 256, 0, stream>>>(x, ln1w + l * 768, ln1b + l * 768, hbf);
    gemm_qkv256<<<dim3(2304 / 128, 4096 / 256), 512, 0, stream>>>(
        hbf, wTl + QKV_T_OFF, qkvb + l * 2304, qb, kbf, vtb, 4096, 2304, 768);
    attn_mfma<<<dim3(8, 12, 4), 512, 0, stream>>>(qb, kbf, vtb, ybf);
    gemm_n64s<<<dim3(768 / 64, 4096 / 64), 256, 0, stream>>>(
        ybf, wTl + AP_T_OFF, apb + l * 768, x, x, 4096, 768, 768);
    ln_kernel<<<1024, 256, 0, stream>>>(x, ln2w + l * 768, ln2b + l * 768, hbf);
    gemm_fc256<<<dim3(3072 / 128, 4096 / 256), 512, 0, stream>>>(
        hbf, wTl + FC_T_OFF, fcb + l * 3072, gbf, 4096, 3072, 768);
    gemm_n64<<<dim3(768 / 64, 4096 / 128), 256, 0, stream>>>(
        gbf, wTl + MP_T_OFF, mpb + l * 768, x, x, 4096, 768, 3072);
  }
  ln_kernel<<<1024, 256, 0, stream>>>(x, lnfw, lnfb, hbf);
  gemm_head<<<dim3((VOC + 127) / 128, 4096 / 256), 512, 0, stream>>>(
      hbf, wtebf, logits, lossPart, 4096, VOC, 768, (VOC + 127) / 128);
  loss_rows2<<<4096, 64, 0, stream>>>(lossPart, logits, targets, nll, (VOC + 127) / 128);
  loss_final<<<1, 256, 0, stream>>>(nll, lossOut);
}

// Round 14
// 2901.175 us; speedup vs baseline: 1.0270x; 1.0270x over previous
//
#include <hip/hip_runtime.h>
#include <hip/hip_bf16.h>

typedef __attribute__((ext_vector_type(8))) short short8;
typedef __attribute__((ext_vector_type(4))) short shortv4;
typedef __attribute__((ext_vector_type(4))) float f32x4;

static constexpr int VOC = 50257;
// per-layer transposed-weight region layout (bf16 elements)
static constexpr size_t QKV_T_OFF = 0;
static constexpr size_t AP_T_OFF  = 1769472;            // 2304*768
static constexpr size_t FC_T_OFF  = 2359296;            // + 768*768
static constexpr size_t MP_T_OFF  = 4718592;            // + 3072*768
static constexpr size_t LSTR      = 7077888;            // + 768*3072

__device__ inline unsigned short f2bf(float f){
  unsigned u = __float_as_uint(f);
  unsigned r = (u + 0x7fffu + ((u >> 16) & 1u)) >> 16;
  return (unsigned short)r;
}

// ---------------- embedding ----------------
__global__ __launch_bounds__(192) void embed_kernel(const int* __restrict__ idx,
    const float* __restrict__ wte, const float* __restrict__ wpe, float* __restrict__ x){
  int row = blockIdx.x;              // b*1024+t
  int t = row & 1023;
  int id = idx[row];
  const float* w = wte + (size_t)id * 768;
  const float* p = wpe + (size_t)t * 768;
  float* o = x + (size_t)row * 768;
  int c = threadIdx.x * 4;
  float4 a = *(const float4*)(w + c);
  float4 b = *(const float4*)(p + c);
  float4 r; r.x = a.x + b.x; r.y = a.y + b.y; r.z = a.z + b.z; r.w = a.w + b.w;
  *(float4*)(o + c) = r;
}

// ---------------- layernorm: 1 wave per row, float4 loads, shfl-only ----------------
__global__ __launch_bounds__(256) void ln_kernel(const float* __restrict__ x,
    const float* __restrict__ w, const float* __restrict__ b,
    unsigned short* __restrict__ out){
  int row  = blockIdx.x * 4 + (threadIdx.x >> 6);
  int lane = threadIdx.x & 63;
  const float* xr = x + (size_t)row * 768;
  float4 v0 = *(const float4*)(xr + lane * 4);
  float4 v1 = *(const float4*)(xr + 256 + lane * 4);
  float4 v2 = *(const float4*)(xr + 512 + lane * 4);
  float s = (v0.x + v0.y + v0.z + v0.w) + (v1.x + v1.y + v1.z + v1.w)
          + (v2.x + v2.y + v2.z + v2.w);
  #pragma unroll
  for (int o = 32; o; o >>= 1) s += __shfl_xor(s, o, 64);
  float mu = s * (1.f / 768.f);
  float q =
    (v0.x-mu)*(v0.x-mu) + (v0.y-mu)*(v0.y-mu) + (v0.z-mu)*(v0.z-mu) + (v0.w-mu)*(v0.w-mu) +
    (v1.x-mu)*(v1.x-mu) + (v1.y-mu)*(v1.y-mu) + (v1.z-mu)*(v1.z-mu) + (v1.w-mu)*(v1.w-mu) +
    (v2.x-mu)*(v2.x-mu) + (v2.y-mu)*(v2.y-mu) + (v2.z-mu)*(v2.z-mu) + (v2.w-mu)*(v2.w-mu);
  #pragma unroll
  for (int o = 32; o; o >>= 1) q += __shfl_xor(q, o, 64);
  float rstd = rsqrtf(q * (1.f / 768.f) + 1e-5f);
  unsigned short* orow = out + (size_t)row * 768;
  #pragma unroll
  for (int seg = 0; seg < 3; seg++){
    float4 v = seg == 0 ? v0 : (seg == 1 ? v1 : v2);
    float4 wv = *(const float4*)(w + seg * 256 + lane * 4);
    float4 bv = *(const float4*)(b + seg * 256 + lane * 4);
    shortv4 o4;
    o4[0] = (short)f2bf((v.x - mu) * rstd * wv.x + bv.x);
    o4[1] = (short)f2bf((v.y - mu) * rstd * wv.y + bv.y);
    o4[2] = (short)f2bf((v.z - mu) * rstd * wv.z + bv.z);
    o4[3] = (short)f2bf((v.w - mu) * rstd * wv.w + bv.w);
    *(shortv4*)(orow + seg * 256 + lane * 4) = o4;
  }
}

// ---------------- batched transpose+cvt of all 4 weight families ----------------
__global__ void transpose_all(const float* __restrict__ qkvw, const float* __restrict__ apw,
    const float* __restrict__ fcw, const float* __restrict__ mpw,
    unsigned short* __restrict__ dst){
  __shared__ float t[32][33];
  int l = blockIdx.y;
  int tile = blockIdx.x;
  const float* W; unsigned short* D; int K, N, ntx, tl;
  if (tile < 1728){      W = qkvw + (size_t)l * 768 * 2304; D = dst + (size_t)l * LSTR + QKV_T_OFF; K = 768;  N = 2304; ntx = 72; tl = tile; }
  else if (tile < 2304){ W = apw  + (size_t)l * 768 * 768;  D = dst + (size_t)l * LSTR + AP_T_OFF;  K = 768;  N = 768;  ntx = 24; tl = tile - 1728; }
  else if (tile < 4608){ W = fcw  + (size_t)l * 768 * 3072; D = dst + (size_t)l * LSTR + FC_T_OFF;  K = 768;  N = 3072; ntx = 96; tl = tile - 2304; }
  else {                 W = mpw  + (size_t)l * 3072 * 768; D = dst + (size_t)l * LSTR + MP_T_OFF;  K = 3072; N = 768;  ntx = 24; tl = tile - 4608; }
  int n0 = (tl % ntx) * 32, k0 = (tl / ntx) * 32;
  int tx = threadIdx.x, ty = threadIdx.y; // (32,8)
  #pragma unroll
  for (int i = 0; i < 4; i++)
    t[ty + i * 8][tx] = W[(size_t)(k0 + ty + i * 8) * N + n0 + tx];
  __syncthreads();
  #pragma unroll
  for (int i = 0; i < 4; i++)
    D[(size_t)(n0 + ty + i * 8) * K + k0 + tx] = f2bf(t[tx][ty + i * 8]);
}

// ---------------- elementwise f32 -> bf16 ----------------
__global__ void cvt_bf16_kernel(const float* __restrict__ src, unsigned short* __restrict__ dst, int n4){
  int i = blockIdx.x * blockDim.x + threadIdx.x;
  int stride = gridDim.x * blockDim.x;
  for (; i < n4; i += stride){
    float4 v = *(const float4*)(src + (size_t)i * 4);
    size_t o = (size_t)i * 4;
    dst[o + 0] = f2bf(v.x); dst[o + 1] = f2bf(v.y);
    dst[o + 2] = f2bf(v.z); dst[o + 3] = f2bf(v.w);
  }
}

// ======== 256x128 main-loop macro: BK=64, 8 waves (4Mx2N), 512 thr ========
#define GEMM256_MAIN_LOOP(CLAMP_B)                                                  \
  f32x4 acc[4][4];                                                                  \
  _Pragma("unroll")                                                                 \
  for (int m = 0; m < 4; m++)                                                       \
    _Pragma("unroll")                                                               \
    for (int n = 0; n < 4; n++)                                                     \
      acc[m][n] = (f32x4){0.f, 0.f, 0.f, 0.f};                                      \
  for (int k0 = 0; k0 < K; k0 += 64){                                               \
    _Pragma("unroll")                                                               \
    for (int i = 0; i < 4; i++){                                                    \
      int p = (i * 8 + wid) * 64 + lane;                                            \
      int r = p >> 3, c = p & 7;                                                    \
      int cs = c ^ (r & 7);                                                         \
      const unsigned short* g = A + (size_t)(brow + r) * K + k0 + cs * 8;           \
      __builtin_amdgcn_global_load_lds(                                             \
        (const __attribute__((address_space(1))) unsigned int*)g,                   \
        (__attribute__((address_space(3))) unsigned int*)(tA + (size_t)(i * 8 + wid) * 64 * 8), \
        16, 0, 0);                                                                  \
    }                                                                               \
    _Pragma("unroll")                                                               \
    for (int i = 0; i < 2; i++){                                                    \
      int p = (i * 8 + wid) * 64 + lane;                                            \
      int r = p >> 3, c = p & 7;                                                    \
      int cs = c ^ (r & 7);                                                         \
      int rc = CLAMP_B;                                                             \
      const unsigned short* g = Bm + (size_t)(bcol + rc) * K + k0 + cs * 8;         \
      __builtin_amdgcn_global_load_lds(                                             \
        (const __attribute__((address_space(1))) unsigned int*)g,                   \
        (__attribute__((address_space(3))) unsigned int*)(tB + (size_t)(i * 8 + wid) * 64 * 8), \
        16, 0, 0);                                                                  \
    }                                                                               \
    __syncthreads();                                                                \
    _Pragma("unroll")                                                               \
    for (int kk = 0; kk < 2; kk++){                                                 \
      short8 av[4], bv[4];                                                          \
      _Pragma("unroll")                                                             \
      for (int m = 0; m < 4; m++){                                                  \
        int R = wr * 64 + m * 16 + lr;                                              \
        int c = kk * 4 + lk;                                                        \
        av[m] = *(const short8*)&tA[R * 64 + ((c ^ (R & 7)) << 3)];                 \
      }                                                                             \
      _Pragma("unroll")                                                             \
      for (int n = 0; n < 4; n++){                                                  \
        int R = wc * 64 + n * 16 + lr;                                              \
        int c = kk * 4 + lk;                                                        \
        bv[n] = *(const short8*)&tB[R * 64 + ((c ^ (R & 7)) << 3)];                 \
      }                                                                             \
      _Pragma("unroll")                                                             \
      for (int m = 0; m < 4; m++)                                                   \
        _Pragma("unroll")                                                           \
        for (int n = 0; n < 4; n++)                                                 \
          acc[m][n] = __builtin_amdgcn_mfma_f32_16x16x32_bf16(av[m], bv[n], acc[m][n], 0, 0, 0); \
    }                                                                               \
    __syncthreads();                                                                \
  }

// ---------------- fc GEMM: 256x128, bias+GELU(fast tanh) -> bf16 ----------------
__global__ __launch_bounds__(512) void gemm_fc256(
    const unsigned short* __restrict__ A,
    const unsigned short* __restrict__ Bm,
    const float* __restrict__ bias,
    unsigned short* __restrict__ outB,
    int M, int N, int K)
{
  __shared__ unsigned short tA[16384];
  __shared__ unsigned short tB[8192];
  const int lane = threadIdx.x & 63;
  const int wid  = threadIdx.x >> 6;
  const int wr = wid >> 1, wc = wid & 1;
  const int lr = lane & 15, lk = lane >> 4;
  const int nbx = gridDim.x, nby = gridDim.y;
  const int nwg = nbx * nby;
  const int lin = blockIdx.y * nbx + blockIdx.x;
  const int qq = nwg >> 3, rr8 = nwg & 7;
  const int xcd = lin & 7, loc = lin >> 3;
  const int wg = (xcd < rr8 ? xcd * (qq + 1) : rr8 * (qq + 1) + (xcd - rr8) * qq) + loc;
  const int mblk = wg / nbx, nblk = wg % nbx;
  const int brow = mblk * 256;
  const int bcol = nblk * 128;

  GEMM256_MAIN_LOOP(r)

  #pragma unroll
  for (int m = 0; m < 4; m++){
    #pragma unroll
    for (int n = 0; n < 4; n++){
      int col = bcol + wc * 64 + n * 16 + lr;
      float bco = bias[col];
      #pragma unroll
      for (int j = 0; j < 4; j++){
        int row = brow + wr * 64 + m * 16 + lk * 4 + j;
        float v = acc[m][n][j] + bco;
        float z = 0.79788456080286536f * (v + 0.044715f * v * v * v);
        float az = fabsf(z);
        float e = __expf(-2.f * az);
        float t = (1.f - e) / (1.f + e);
        t = z < 0.f ? -t : t;
        v = 0.5f * v * (1.f + t);
        outB[(size_t)row * N + col] = f2bf(v);
      }
    }
  }
}

// ---------------- QKV GEMM 256x128 with fused repack ----------------
__global__ __launch_bounds__(512) void gemm_qkv256(
    const unsigned short* __restrict__ A,
    const unsigned short* __restrict__ Bm,
    const float* __restrict__ bias,
    unsigned short* __restrict__ Qb,   // [BH,1024,64]
    unsigned short* __restrict__ Kb,
    unsigned short* __restrict__ VT,   // [BH,64,1024]
    int M, int N, int K)
{
  __shared__ unsigned short tA[16384];
  __shared__ unsigned short tB[8192];
  const int lane = threadIdx.x & 63;
  const int wid  = threadIdx.x >> 6;
  const int wr = wid >> 1, wc = wid & 1;
  const int lr = lane & 15, lk = lane >> 4;
  const int nbx = gridDim.x, nby = gridDim.y;
  const int nwg = nbx * nby;
  const int lin = blockIdx.y * nbx + blockIdx.x;
  const int qq = nwg >> 3, rr8 = nwg & 7;
  const int xcd = lin & 7, loc = lin >> 3;
  const int wg = (xcd < rr8 ? xcd * (qq + 1) : rr8 * (qq + 1) + (xcd - rr8) * qq) + loc;
  const int mblk = wg / nbx, nblk = wg % nbx;
  const int brow = mblk * 256;         // never spans a 1024-row batch boundary
  const int bcol = nblk * 128;

  GEMM256_MAIN_LOOP(r)

  const int b = brow >> 10, tstart = brow & 1023;
  if (bcol < 1536){
    // Q or K scatter: [BH, t, 64] bf16
    #pragma unroll
    for (int m = 0; m < 4; m++)
      #pragma unroll
      for (int n = 0; n < 4; n++){
        int col = bcol + wc * 64 + n * 16 + lr;
        float bco = bias[col];
        int isK = col >= 768;
        int h = (isK ? col - 768 : col) >> 6;
        unsigned short* dstp = isK ? Kb : Qb;
        #pragma unroll
        for (int j = 0; j < 4; j++){
          int t = tstart + wr * 64 + m * 16 + lk * 4 + j;
          dstp[(((size_t)b * 12 + h) * 1024 + t) * 64 + (col & 63)] =
              f2bf(acc[m][n][j] + bco);
        }
      }
  } else {
    // V: transpose 256x128 in four 64-row passes through 64x136 LDS (in tA)
    unsigned short* sh = tA;   // 8704 shorts used
    const int h0 = (bcol - 1536) >> 6;
    #pragma unroll
    for (int half = 0; half < 4; half++){
      __syncthreads();
      if (wr == half){
        #pragma unroll
        for (int m = 0; m < 4; m++)
          #pragma unroll
          for (int n = 0; n < 4; n++){
            int lcol = wc * 64 + n * 16 + lr;
            float bco = bias[bcol + lcol];
            #pragma unroll
            for (int j = 0; j < 4; j++)
              sh[(m * 16 + lk * 4 + j) * 136 + lcol] = f2bf(acc[m][n][j] + bco);
          }
      }
      __syncthreads();
      int c_local = threadIdx.x & 127, tpart = threadIdx.x >> 7; // 0..3 (16 rows each)
      int h = h0 + (c_local >> 6);
      int d = c_local & 63;
      unsigned short* vrow = VT + (((size_t)b * 12 + h) * 64 + d) * 1024
                           + tstart + half * 64 + tpart * 16;
      #pragma unroll
      for (int i = 0; i < 2; i++){
        short8 pk;
        #pragma unroll
        for (int s2 = 0; s2 < 8; s2++)
          pk[s2] = (short)sh[(tpart * 16 + i * 8 + s2) * 136 + c_local];
        *(short8*)&vrow[i * 8] = pk;
      }
    }
  }
}

// ---------------- small-N GEMM: BM=128 x BN=64, 4 waves (2Mx2N, wave 64x32) ----------------
__global__ __launch_bounds__(256) void gemm_n64(
    const unsigned short* __restrict__ A,
    const unsigned short* __restrict__ Bm,
    const float* __restrict__ bias,
    const float* __restrict__ resid,
    float* __restrict__ outF,
    int M, int N, int K)
{
  __shared__ unsigned short tA[8192];   // 128 x 64
  __shared__ unsigned short tB[4096];   // 64 x 64
  const int lane = threadIdx.x & 63;
  const int wid  = threadIdx.x >> 6;
  const int wr = wid >> 1, wc = wid & 1;
  const int lr = lane & 15, lk = lane >> 4;
  const int nbx = gridDim.x, nby = gridDim.y;   // nbx = N/64
  const int nwg = nbx * nby;
  const int lin = blockIdx.y * nbx + blockIdx.x;
  const int qq = nwg >> 3, rr8 = nwg & 7;
  const int xcd = lin & 7, loc = lin >> 3;
  const int wg = (xcd < rr8 ? xcd * (qq + 1) : rr8 * (qq + 1) + (xcd - rr8) * qq) + loc;
  const int mblk = wg / nbx, nblk = wg % nbx;
  const int brow = mblk * 128;
  const int bcol = nblk * 64;

  f32x4 acc[4][2];
  #pragma unroll
  for (int m = 0; m < 4; m++)
    #pragma unroll
    for (int n = 0; n < 2; n++)
      acc[m][n] = (f32x4){0.f, 0.f, 0.f, 0.f};

  for (int k0 = 0; k0 < K; k0 += 64){
    #pragma unroll
    for (int i = 0; i < 4; i++){
      int p = (i * 4 + wid) * 64 + lane;      // A: 1024 chunks
      int r = p >> 3, c = p & 7;
      int cs = c ^ (r & 7);
      const unsigned short* g = A + (size_t)(brow + r) * K + k0 + cs * 8;
      __builtin_amdgcn_global_load_lds(
        (const __attribute__((address_space(1))) unsigned int*)g,
        (__attribute__((address_space(3))) unsigned int*)(tA + (size_t)(i * 4 + wid) * 64 * 8),
        16, 0, 0);
    }
    #pragma unroll
    for (int i = 0; i < 2; i++){
      int p = (i * 4 + wid) * 64 + lane;      // B: 512 chunks (64 rows)
      int r = p >> 3, c = p & 7;
      int cs = c ^ (r & 7);
      const unsigned short* g = Bm + (size_t)(bcol + r) * K + k0 + cs * 8;
      __builtin_amdgcn_global_load_lds(
        (const __attribute__((address_space(1))) unsigned int*)g,
        (__attribute__((address_space(3))) unsigned int*)(tB + (size_t)(i * 4 + wid) * 64 * 8),
        16, 0, 0);
    }
    __syncthreads();
    #pragma unroll
    for (int kk = 0; kk < 2; kk++){
      short8 av[4], bv[2];
      #pragma unroll
      for (int m = 0; m < 4; m++){
        int R = wr * 64 + m * 16 + lr;
        int c = kk * 4 + lk;
        av[m] = *(const short8*)&tA[R * 64 + ((c ^ (R & 7)) << 3)];
      }
      #pragma unroll
      for (int n = 0; n < 2; n++){
        int R = wc * 32 + n * 16 + lr;
        int c = kk * 4 + lk;
        bv[n] = *(const short8*)&tB[R * 64 + ((c ^ (R & 7)) << 3)];
      }
      #pragma unroll
      for (int m = 0; m < 4; m++)
        #pragma unroll
        for (int n = 0; n < 2; n++)
          acc[m][n] = __builtin_amdgcn_mfma_f32_16x16x32_bf16(av[m], bv[n], acc[m][n], 0, 0, 0);
    }
    __syncthreads();
  }

  #pragma unroll
  for (int m = 0; m < 4; m++){
    #pragma unroll
    for (int n = 0; n < 2; n++){
      int col = bcol + wc * 32 + n * 16 + lr;
      float bco = bias[col];
      #pragma unroll
      for (int j = 0; j < 4; j++){
        int row = brow + wr * 64 + m * 16 + lk * 4 + j;
        float v = acc[m][n][j] + bco + resid[(size_t)row * N + col];
        outF[(size_t)row * N + col] = v;
      }
    }
  }
}

// ---------------- tiny-tile GEMM: BM=64 x BN=64, 4 waves (2Mx2N, wave 32x32) ----------------
__global__ __launch_bounds__(256) void gemm_n64s(
    const unsigned short* __restrict__ A,
    const unsigned short* __restrict__ Bm,
    const float* __restrict__ bias,
    const float* __restrict__ resid,
    float* __restrict__ outF,
    int M, int N, int K)
{
  __shared__ unsigned short tA[4096];   // 64 x 64
  __shared__ unsigned short tB[4096];   // 64 x 64
  const int lane = threadIdx.x & 63;
  const int wid  = threadIdx.x >> 6;
  const int wr = wid >> 1, wc = wid & 1;
  const int lr = lane & 15, lk = lane >> 4;
  const int nbx = gridDim.x, nby = gridDim.y;   // nbx = N/64, nby = M/64
  const int nwg = nbx * nby;
  const int lin = blockIdx.y * nbx + blockIdx.x;
  const int qq = nwg >> 3, rr8 = nwg & 7;
  const int xcd = lin & 7, loc = lin >> 3;
  const int wg = (xcd < rr8 ? xcd * (qq + 1) : rr8 * (qq + 1) + (xcd - rr8) * qq) + loc;
  const int mblk = wg / nbx, nblk = wg % nbx;
  const int brow = mblk * 64;
  const int bcol = nblk * 64;

  f32x4 acc[2][2];
  #pragma unroll
  for (int m = 0; m < 2; m++)
    #pragma unroll
    for (int n = 0; n < 2; n++)
      acc[m][n] = (f32x4){0.f, 0.f, 0.f, 0.f};

  for (int k0 = 0; k0 < K; k0 += 64){
    #pragma unroll
    for (int i = 0; i < 2; i++){
      int p = (i * 4 + wid) * 64 + lane;      // 512 chunks each
      int r = p >> 3, c = p & 7;
      int cs = c ^ (r & 7);
      const unsigned short* ga = A + (size_t)(brow + r) * K + k0 + cs * 8;
      __builtin_amdgcn_global_load_lds(
        (const __attribute__((address_space(1))) unsigned int*)ga,
        (__attribute__((address_space(3))) unsigned int*)(tA + (size_t)(i * 4 + wid) * 64 * 8),
        16, 0, 0);
      const unsigned short* gb = Bm + (size_t)(bcol + r) * K + k0 + cs * 8;
      __builtin_amdgcn_global_load_lds(
        (const __attribute__((address_space(1))) unsigned int*)gb,
        (__attribute__((address_space(3))) unsigned int*)(tB + (size_t)(i * 4 + wid) * 64 * 8),
        16, 0, 0);
    }
    __syncthreads();
    #pragma unroll
    for (int kk = 0; kk < 2; kk++){
      short8 av[2], bv[2];
      #pragma unroll
      for (int m = 0; m < 2; m++){
        int R = wr * 32 + m * 16 + lr;
        int c = kk * 4 + lk;
        av[m] = *(const short8*)&tA[R * 64 + ((c ^ (R & 7)) << 3)];
      }
      #pragma unroll
      for (int n = 0; n < 2; n++){
        int R = wc * 32 + n * 16 + lr;
        int c = kk * 4 + lk;
        bv[n] = *(const short8*)&tB[R * 64 + ((c ^ (R & 7)) << 3)];
      }
      #pragma unroll
      for (int m = 0; m < 2; m++)
        #pragma unroll
        for (int n = 0; n < 2; n++)
          acc[m][n] = __builtin_amdgcn_mfma_f32_16x16x32_bf16(av[m], bv[n], acc[m][n], 0, 0, 0);
    }
    __syncthreads();
  }

  #pragma unroll
  for (int m = 0; m < 2; m++){
    #pragma unroll
    for (int n = 0; n < 2; n++){
      int col = bcol + wc * 32 + n * 16 + lr;
      float bco = bias[col];
      #pragma unroll
      for (int j = 0; j < 4; j++){
        int row = brow + wr * 32 + m * 16 + lk * 4 + j;
        float v = acc[m][n][j] + bco + resid[(size_t)row * N + col];
        outF[(size_t)row * N + col] = v;
      }
    }
  }
}

// ---------------- lm_head GEMM: BM=256 x BN=128, 512 threads (8 waves 4Mx2N) ----------------
__global__ __launch_bounds__(512) void gemm_head(
    const unsigned short* __restrict__ A,
    const unsigned short* __restrict__ Bm,
    float* __restrict__ outF,
    float2* __restrict__ lossPart,
    int M, int N, int K, int nPart)
{
  __shared__ unsigned short tA[16384];   // 256 x 64
  __shared__ unsigned short tB[8192];    // 128 x 64
  const int lane = threadIdx.x & 63;
  const int wid  = threadIdx.x >> 6;     // 0..7
  const int wr = wid >> 1, wc = wid & 1; // wr 0..3, wc 0..1
  const int lr = lane & 15, lk = lane >> 4;
  const int nblk = blockIdx.x, mblk = blockIdx.y;  // plain N-fastest
  const int brow = mblk * 256;
  const int bcol = nblk * 128;
  const int nValid = N - bcol;

  GEMM256_MAIN_LOOP(r < nValid ? r : (nValid - 1))

  #pragma unroll
  for (int m = 0; m < 4; m++){
    #pragma unroll
    for (int n = 0; n < 4; n++){
      int col = bcol + wc * 64 + n * 16 + lr;
      if (col < N){
        #pragma unroll
        for (int j = 0; j < 4; j++){
          int row = brow + wr * 64 + m * 16 + lk * 4 + j;
          outF[(size_t)row * N + col] = acc[m][n][j];
        }
      }
    }
  }

  // fused loss partials: per row (max, sum_exp) over this 128-col slice
  float* mred = (float*)tA;          // 512+512 floats, safe after final barrier
  float* sred = mred + 512;
  #pragma unroll
  for (int m = 0; m < 4; m++){
    #pragma unroll
    for (int j = 0; j < 4; j++){
      float vv[4];
      float mx = -3.4e38f;
      #pragma unroll
      for (int n = 0; n < 4; n++){
        int col = bcol + wc * 64 + n * 16 + lr;
        vv[n] = (col < N) ? acc[m][n][j] : -3.4e38f;
        mx = fmaxf(mx, vv[n]);
      }
      #pragma unroll
      for (int msk = 1; msk < 16; msk <<= 1)
        mx = fmaxf(mx, __shfl_xor(mx, msk, 64));
      float sm = 0.f;
      #pragma unroll
      for (int n = 0; n < 4; n++){
        int col = bcol + wc * 64 + n * 16 + lr;
        if (col < N) sm += __expf(vv[n] - mx);
      }
      #pragma unroll
      for (int msk = 1; msk < 16; msk <<= 1)
        sm += __shfl_xor(sm, msk, 64);
      if (lr == 0){
        int rid = (wr * 2 + wc) * 64 + m * 16 + lk * 4 + j;   // [0,512)
        mred[rid] = mx; sred[rid] = sm;
      }
    }
  }
  __syncthreads();
  if (threadIdx.x < 256){
    int wrq = threadIdx.x >> 6, rowi = threadIdx.x & 63;       // wrq 0..3
    float m0 = mred[(wrq * 2 + 0) * 64 + rowi];
    float m1 = mred[(wrq * 2 + 1) * 64 + rowi];
    float s0 = sred[(wrq * 2 + 0) * 64 + rowi];
    float s1 = sred[(wrq * 2 + 1) * 64 + rowi];
    float Mv = fmaxf(m0, m1);
    float Sv = (s0 > 0.f ? s0 * __expf(m0 - Mv) : 0.f)
             + (s1 > 0.f ? s1 * __expf(m1 - Mv) : 0.f);
    int grow = brow + wrq * 64 + rowi;
    lossPart[(size_t)grow * nPart + nblk] = make_float2(Mv, Sv);
  }
}

// ---------------- MFMA flash attention: QBLK=64, 4 waves (round-12 best) + setprio ----------------
__global__ __launch_bounds__(256) void attn_mfma(
    const unsigned short* __restrict__ Qb,   // [BH,1024,64]
    const unsigned short* __restrict__ Kb,   // [BH,1024,64]
    const unsigned short* __restrict__ VT,   // [BH,64,1024]
    unsigned short* __restrict__ y)          // [B*T,768]
{
  __shared__ unsigned short Kl[64 * 64];
  __shared__ unsigned short Vl[64 * 64];
  __shared__ unsigned short Pl[4][16 * 72];
  const int xq = blockIdx.x;
  const int qt = (xq & 1) ? (xq >> 1) : (15 - (xq >> 1)); // interleave heavy/light
  const int h = blockIdx.y, b = blockIdx.z;
  const size_t bh = (size_t)(b * 12 + h);
  const int lane = threadIdx.x & 63;
  const int w = threadIdx.x >> 6;
  const int lr = lane & 15, lk = lane >> 4;

  short8 aq[2];
  {
    const unsigned short* qrow = Qb + ((bh * 1024) + qt * 64 + w * 16 + lr) * 64;
    aq[0] = *(const short8*)&qrow[lk * 8];
    aq[1] = *(const short8*)&qrow[32 + lk * 8];
  }

  f32x4 o[4];
  #pragma unroll
  for (int n = 0; n < 4; n++) o[n] = (f32x4){0.f, 0.f, 0.f, 0.f};
  float mold[4] = {-1e30f, -1e30f, -1e30f, -1e30f};
  float lsum[4] = {0.f, 0.f, 0.f, 0.f};

  for (int kt = 0; kt <= qt; kt++){
    #pragma unroll
    for (int i = 0; i < 2; i++){
      int p = (i * 4 + w) * 64 + lane;
      int r = p >> 3, c = p & 7;
      int cs = c ^ (r & 7);
      const unsigned short* gk = Kb + (bh * 1024 + (size_t)kt * 64 + r) * 64 + cs * 8;
      __builtin_amdgcn_global_load_lds(
        (const __attribute__((address_space(1))) unsigned int*)gk,
        (__attribute__((address_space(3))) unsigned int*)(Kl + (size_t)(i * 4 + w) * 64 * 8),
        16, 0, 0);
      const unsigned short* gv = VT + (bh * 64 + r) * 1024 + (size_t)kt * 64 + cs * 8;
      __builtin_amdgcn_global_load_lds(
        (const __attribute__((address_space(1))) unsigned int*)gv,
        (__attribute__((address_space(3))) unsigned int*)(Vl + (size_t)(i * 4 + w) * 64 * 8),
        16, 0, 0);
    }
    __syncthreads();

    f32x4 s[4];
    #pragma unroll
    for (int n = 0; n < 4; n++) s[n] = (f32x4){0.f, 0.f, 0.f, 0.f};
    __builtin_amdgcn_s_setprio(1);
    #pragma unroll
    for (int ck = 0; ck < 2; ck++){
      #pragma unroll
      for (int n = 0; n < 4; n++){
        int R = n * 16 + lr, c = ck * 4 + lk;
        short8 bv = *(const short8*)&Kl[R * 64 + ((c ^ (R & 7)) << 3)];
        s[n] = __builtin_amdgcn_mfma_f32_16x16x32_bf16(aq[ck], bv, s[n], 0, 0, 0);
      }
    }
    __builtin_amdgcn_s_setprio(0);
    #pragma unroll
    for (int n = 0; n < 4; n++)
      #pragma unroll
      for (int j = 0; j < 4; j++){
        float v = s[n][j] * 0.125f;
        if (kt == qt && (n * 16 + lr) > (w * 16 + lk * 4 + j)) v = -1e30f;
        s[n][j] = v;
      }
    float mt[4];
    #pragma unroll
    for (int j = 0; j < 4; j++)
      mt[j] = fmaxf(fmaxf(s[0][j], s[1][j]), fmaxf(s[2][j], s[3][j]));
    #pragma unroll
    for (int msk = 1; msk < 16; msk <<= 1)
      #pragma unroll
      for (int j = 0; j < 4; j++)
        mt[j] = fmaxf(mt[j], __shfl_xor(mt[j], msk, 64));
    #pragma unroll
    for (int j = 0; j < 4; j++){
      float mn = fmaxf(mold[j], mt[j]);
      float a = __expf(mold[j] - mn);
      mold[j] = mn;
      lsum[j] *= a;
      #pragma unroll
      for (int n = 0; n < 4; n++){
        float p = __expf(s[n][j] - mn);
        s[n][j] = p;
        lsum[j] += p;
      }
      #pragma unroll
      for (int n2 = 0; n2 < 4; n2++) o[n2][j] *= a;
    }
    #pragma unroll
    for (int n = 0; n < 4; n++)
      #pragma unroll
      for (int j = 0; j < 4; j++)
        Pl[w][(lk * 4 + j) * 72 + n * 16 + lr] = f2bf(s[n][j]);
    __syncthreads();
    __builtin_amdgcn_s_setprio(1);
    #pragma unroll
    for (int ck = 0; ck < 2; ck++){
      short8 pa = *(const short8*)&Pl[w][lr * 72 + ck * 32 + lk * 8];
      #pragma unroll
      for (int n2 = 0; n2 < 4; n2++){
        int R = n2 * 16 + lr, c = ck * 4 + lk;
        short8 vv = *(const short8*)&Vl[R * 64 + ((c ^ (R & 7)) << 3)];
        o[n2] = __builtin_amdgcn_mfma_f32_16x16x32_bf16(pa, vv, o[n2], 0, 0, 0);
      }
    }
    __builtin_amdgcn_s_setprio(0);
    __syncthreads();
  }

  #pragma unroll
  for (int msk = 1; msk < 16; msk <<= 1)
    #pragma unroll
    for (int j = 0; j < 4; j++)
      lsum[j] += __shfl_xor(lsum[j], msk, 64);
  float inv[4];
  #pragma unroll
  for (int j = 0; j < 4; j++) inv[j] = 1.f / lsum[j];

  #pragma unroll
  for (int n2 = 0; n2 < 4; n2++)
    #pragma unroll
    for (int j = 0; j < 4; j++){
      size_t row = (size_t)(b * 1024 + qt * 64 + w * 16 + lk * 4 + j);
      y[row * 768 + h * 64 + n2 * 16 + lr] = f2bf(o[n2][j] * inv[j]);
    }
}

// ---------------- loss: combine per-block partials ----------------
__global__ __launch_bounds__(64) void loss_rows2(const float2* __restrict__ part,
    const float* __restrict__ logits, const int* __restrict__ targets,
    float* __restrict__ nll, int nPart){
  int row = blockIdx.x, lane = threadIdx.x;
  float m = -3.4e38f, s = 0.f;
  for (int i = lane; i < nPart; i += 64){
    float2 p = part[(size_t)row * nPart + i];
    if (p.y > 0.f){
      float nm = fmaxf(m, p.x);
      s = s * __expf(m - nm) + p.y * __expf(p.x - nm);
      m = nm;
    }
  }
  #pragma unroll
  for (int o = 32; o; o >>= 1){
    float m2 = __shfl_xor(m, o, 64);
    float s2 = __shfl_xor(s, o, 64);
    float nm = fmaxf(m, m2);
    s = s * __expf(m - nm) + s2 * __expf(m2 - nm);
    m = nm;
  }
  if (lane == 0)
    nll[row] = m + logf(s) - logits[(size_t)row * VOC + targets[row]];
}

__global__ __launch_bounds__(256) void loss_final(const float* __restrict__ nll,
                                                  float* __restrict__ out){
  __shared__ float red[4];
  int tid = threadIdx.x;
  float s = 0.f;
  for (int i = tid; i < 4096; i += 256) s += nll[i];
  #pragma unroll
  for (int o = 32; o; o >>= 1) s += __shfl_xor(s, o, 64);
  if ((tid & 63) == 0) red[tid >> 6] = s;
  __syncthreads();
  if (tid == 0) out[0] = (red[0] + red[1] + red[2] + red[3]) * (1.f / 4096.f);
}

// ---------------- host ----------------
extern "C" void kernel_launch(void* const* d_in, const int* in_sizes, int n_in,
                              void* d_out, int out_size, void* d_ws, size_t ws_size,
                              hipStream_t stream){
  (void)in_sizes; (void)n_in; (void)out_size;
  const int*   idx     = (const int*)d_in[0];
  const int*   targets = (const int*)d_in[1];
  const float* wte     = (const float*)d_in[2];
  const float* wpe     = (const float*)d_in[3];
  const float* ln1w    = (const float*)d_in[4];
  const float* ln1b    = (const float*)d_in[5];
  const float* qkvw    = (const float*)d_in[6];
  const float* qkvb    = (const float*)d_in[7];
  const float* apw     = (const float*)d_in[8];
  const float* apb     = (const float*)d_in[9];
  const float* ln2w    = (const float*)d_in[10];
  const float* ln2b    = (const float*)d_in[11];
  const float* fcw     = (const float*)d_in[12];
  const float* fcb     = (const float*)d_in[13];
  const float* mpw     = (const float*)d_in[14];
  const float* mpb     = (const float*)d_in[15];
  const float* lnfw    = (const float*)d_in[16];
  const float* lnfb    = (const float*)d_in[17];

  char* ws = (char*)d_ws;
  size_t off = 0;
  auto alloc = [&](size_t bytes){
    void* p = ws + off; off += (bytes + 255) & ~(size_t)255; return p;
  };
  float* x               = (float*)alloc((size_t)4096 * 768 * 4);
  unsigned short* hbf    = (unsigned short*)alloc((size_t)4096 * 768 * 2);
  unsigned short* ybf    = (unsigned short*)alloc((size_t)4096 * 768 * 2);
  unsigned short* gbf    = (unsigned short*)alloc((size_t)4096 * 3072 * 2);
  unsigned short* wtebf  = (unsigned short*)alloc((size_t)VOC * 768 * 2);
  unsigned short* qb     = (unsigned short*)alloc((size_t)48 * 1024 * 64 * 2);
  unsigned short* kbf    = (unsigned short*)alloc((size_t)48 * 1024 * 64 * 2);
  unsigned short* vtb    = (unsigned short*)alloc((size_t)48 * 1024 * 64 * 2);
  float2* lossPart       = (float2*)alloc((size_t)4096 * 393 * 8);
  float* nll             = (float*)alloc((size_t)4096 * 4);
  // transposed weights: all 12 layers if ws allows, else per-layer ping buffer
  bool mega = (ws_size - off) >= (12 * LSTR * 2 + 256);
  unsigned short* wTall = (unsigned short*)alloc(mega ? 12 * LSTR * 2 : LSTR * 2);

  float* logits  = (float*)d_out;
  float* lossOut = logits + (size_t)4096 * VOC;

  cvt_bf16_kernel<<<2048, 256, 0, stream>>>(wte, wtebf, (VOC * 768) / 4);
  embed_kernel<<<4096, 192, 0, stream>>>(idx, wte, wpe, x);
  if (mega)
    transpose_all<<<dim3(6912, 12), dim3(32, 8), 0, stream>>>(qkvw, apw, fcw, mpw, wTall);

  for (int l = 0; l < 12; l++){
    unsigned short* wTl = wTall;
    if (mega) wTl = wTall + (size_t)l * LSTR;
    else
      transpose_all<<<dim3(6912, 1), dim3(32, 8), 0, stream>>>(
          qkvw + (size_t)l * 768 * 2304, apw + (size_t)l * 768 * 768,
          fcw + (size_t)l * 768 * 3072, mpw + (size_t)l * 3072 * 768, wTall);

    ln_kernel<<<1024, 256, 0, stream>>>(x, ln1w + l * 768, ln1b + l * 768, hbf);
    gemm_qkv256<<<dim3(2304 / 128, 4096 / 256), 512, 0, stream>>>(
        hbf, wTl + QKV_T_OFF, qkvb + l * 2304, qb, kbf, vtb, 4096, 2304, 768);
    attn_mfma<<<dim3(16, 12, 4), 256, 0, stream>>>(qb, kbf, vtb, ybf);
    gemm_n64s<<<dim3(768 / 64, 4096 / 64), 256, 0, stream>>>(
        ybf, wTl + AP_T_OFF, apb + l * 768, x, x, 4096, 768, 768);
    ln_kernel<<<1024, 256, 0, stream>>>(x, ln2w + l * 768, ln2b + l * 768, hbf);
    gemm_fc256<<<dim3(3072 / 128, 4096 / 256), 512, 0, stream>>>(
        hbf, wTl + FC_T_OFF, fcb + l * 3072, gbf, 4096, 3072, 768);
    gemm_n64<<<dim3(768 / 64, 4096 / 128), 256, 0, stream>>>(
        gbf, wTl + MP_T_OFF, mpb + l * 768, x, x, 4096, 768, 3072);
  }
  ln_kernel<<<1024, 256, 0, stream>>>(x, lnfw, lnfb, hbf);
  gemm_head<<<dim3((VOC + 127) / 128, 4096 / 256), 512, 0, stream>>>(
      hbf, wtebf, logits, lossPart, 4096, VOC, 768, (VOC + 127) / 128);
  loss_rows2<<<4096, 64, 0, stream>>>(lossPart, logits, targets, nll, (VOC + 127) / 128);
  loss_final<<<1, 256, 0, stream>>>(nll, lossOut);
}

// Round 15
// 2888.163 us; speedup vs baseline: 1.0316x; 1.0045x over previous
//
#include <hip/hip_runtime.h>
#include <hip/hip_bf16.h>

typedef __attribute__((ext_vector_type(8))) short short8;
typedef __attribute__((ext_vector_type(4))) short shortv4;
typedef __attribute__((ext_vector_type(4))) float f32x4;

static constexpr int VOC = 50257;
// per-layer transposed-weight region layout (bf16 elements)
static constexpr size_t QKV_T_OFF = 0;
static constexpr size_t AP_T_OFF  = 1769472;            // 2304*768
static constexpr size_t FC_T_OFF  = 2359296;            // + 768*768
static constexpr size_t MP_T_OFF  = 4718592;            // + 3072*768
static constexpr size_t LSTR      = 7077888;            // + 768*3072

__device__ inline unsigned short f2bf(float f){
  unsigned u = __float_as_uint(f);
  unsigned r = (u + 0x7fffu + ((u >> 16) & 1u)) >> 16;
  return (unsigned short)r;
}

// ---------------- embedding ----------------
__global__ __launch_bounds__(192) void embed_kernel(const int* __restrict__ idx,
    const float* __restrict__ wte, const float* __restrict__ wpe, float* __restrict__ x){
  int row = blockIdx.x;              // b*1024+t
  int t = row & 1023;
  int id = idx[row];
  const float* w = wte + (size_t)id * 768;
  const float* p = wpe + (size_t)t * 768;
  float* o = x + (size_t)row * 768;
  int c = threadIdx.x * 4;
  float4 a = *(const float4*)(w + c);
  float4 b = *(const float4*)(p + c);
  float4 r; r.x = a.x + b.x; r.y = a.y + b.y; r.z = a.z + b.z; r.w = a.w + b.w;
  *(float4*)(o + c) = r;
}

// ---------------- layernorm: 1 wave per row, float4 loads, shfl-only ----------------
__global__ __launch_bounds__(256) void ln_kernel(const float* __restrict__ x,
    const float* __restrict__ w, const float* __restrict__ b,
    unsigned short* __restrict__ out){
  int row  = blockIdx.x * 4 + (threadIdx.x >> 6);
  int lane = threadIdx.x & 63;
  const float* xr = x + (size_t)row * 768;
  float4 v0 = *(const float4*)(xr + lane * 4);
  float4 v1 = *(const float4*)(xr + 256 + lane * 4);
  float4 v2 = *(const float4*)(xr + 512 + lane * 4);
  float s = (v0.x + v0.y + v0.z + v0.w) + (v1.x + v1.y + v1.z + v1.w)
          + (v2.x + v2.y + v2.z + v2.w);
  #pragma unroll
  for (int o = 32; o; o >>= 1) s += __shfl_xor(s, o, 64);
  float mu = s * (1.f / 768.f);
  float q =
    (v0.x-mu)*(v0.x-mu) + (v0.y-mu)*(v0.y-mu) + (v0.z-mu)*(v0.z-mu) + (v0.w-mu)*(v0.w-mu) +
    (v1.x-mu)*(v1.x-mu) + (v1.y-mu)*(v1.y-mu) + (v1.z-mu)*(v1.z-mu) + (v1.w-mu)*(v1.w-mu) +
    (v2.x-mu)*(v2.x-mu) + (v2.y-mu)*(v2.y-mu) + (v2.z-mu)*(v2.z-mu) + (v2.w-mu)*(v2.w-mu);
  #pragma unroll
  for (int o = 32; o; o >>= 1) q += __shfl_xor(q, o, 64);
  float rstd = rsqrtf(q * (1.f / 768.f) + 1e-5f);
  unsigned short* orow = out + (size_t)row * 768;
  #pragma unroll
  for (int seg = 0; seg < 3; seg++){
    float4 v = seg == 0 ? v0 : (seg == 1 ? v1 : v2);
    float4 wv = *(const float4*)(w + seg * 256 + lane * 4);
    float4 bv = *(const float4*)(b + seg * 256 + lane * 4);
    shortv4 o4;
    o4[0] = (short)f2bf((v.x - mu) * rstd * wv.x + bv.x);
    o4[1] = (short)f2bf((v.y - mu) * rstd * wv.y + bv.y);
    o4[2] = (short)f2bf((v.z - mu) * rstd * wv.z + bv.z);
    o4[3] = (short)f2bf((v.w - mu) * rstd * wv.w + bv.w);
    *(shortv4*)(orow + seg * 256 + lane * 4) = o4;
  }
}

// ---------------- batched transpose+cvt of all 4 weight families ----------------
__global__ void transpose_all(const float* __restrict__ qkvw, const float* __restrict__ apw,
    const float* __restrict__ fcw, const float* __restrict__ mpw,
    unsigned short* __restrict__ dst){
  __shared__ float t[32][33];
  int l = blockIdx.y;
  int tile = blockIdx.x;
  const float* W; unsigned short* D; int K, N, ntx, tl;
  if (tile < 1728){      W = qkvw + (size_t)l * 768 * 2304; D = dst + (size_t)l * LSTR + QKV_T_OFF; K = 768;  N = 2304; ntx = 72; tl = tile; }
  else if (tile < 2304){ W = apw  + (size_t)l * 768 * 768;  D = dst + (size_t)l * LSTR + AP_T_OFF;  K = 768;  N = 768;  ntx = 24; tl = tile - 1728; }
  else if (tile < 4608){ W = fcw  + (size_t)l * 768 * 3072; D = dst + (size_t)l * LSTR + FC_T_OFF;  K = 768;  N = 3072; ntx = 96; tl = tile - 2304; }
  else {                 W = mpw  + (size_t)l * 3072 * 768; D = dst + (size_t)l * LSTR + MP_T_OFF;  K = 3072; N = 768;  ntx = 24; tl = tile - 4608; }
  int n0 = (tl % ntx) * 32, k0 = (tl / ntx) * 32;
  int tx = threadIdx.x, ty = threadIdx.y; // (32,8)
  #pragma unroll
  for (int i = 0; i < 4; i++)
    t[ty + i * 8][tx] = W[(size_t)(k0 + ty + i * 8) * N + n0 + tx];
  __syncthreads();
  #pragma unroll
  for (int i = 0; i < 4; i++)
    D[(size_t)(n0 + ty + i * 8) * K + k0 + tx] = f2bf(t[tx][ty + i * 8]);
}

// ---------------- elementwise f32 -> bf16 ----------------
__global__ void cvt_bf16_kernel(const float* __restrict__ src, unsigned short* __restrict__ dst, int n4){
  int i = blockIdx.x * blockDim.x + threadIdx.x;
  int stride = gridDim.x * blockDim.x;
  for (; i < n4; i += stride){
    float4 v = *(const float4*)(src + (size_t)i * 4);
    size_t o = (size_t)i * 4;
    dst[o + 0] = f2bf(v.x); dst[o + 1] = f2bf(v.y);
    dst[o + 2] = f2bf(v.z); dst[o + 3] = f2bf(v.w);
  }
}

// ======== 256x128 main-loop macro: BK=64, 8 waves (4Mx2N), 512 thr ========
#define GEMM256_MAIN_LOOP(CLAMP_B)                                                  \
  f32x4 acc[4][4];                                                                  \
  _Pragma("unroll")                                                                 \
  for (int m = 0; m < 4; m++)                                                       \
    _Pragma("unroll")                                                               \
    for (int n = 0; n < 4; n++)                                                     \
      acc[m][n] = (f32x4){0.f, 0.f, 0.f, 0.f};                                      \
  for (int k0 = 0; k0 < K; k0 += 64){                                               \
    _Pragma("unroll")                                                               \
    for (int i = 0; i < 4; i++){                                                    \
      int p = (i * 8 + wid) * 64 + lane;                                            \
      int r = p >> 3, c = p & 7;                                                    \
      int cs = c ^ (r & 7);                                                         \
      const unsigned short* g = A + (size_t)(brow + r) * K + k0 + cs * 8;           \
      __builtin_amdgcn_global_load_lds(                                             \
        (const __attribute__((address_space(1))) unsigned int*)g,                   \
        (__attribute__((address_space(3))) unsigned int*)(tA + (size_t)(i * 8 + wid) * 64 * 8), \
        16, 0, 0);                                                                  \
    }                                                                               \
    _Pragma("unroll")                                                               \
    for (int i = 0; i < 2; i++){                                                    \
      int p = (i * 8 + wid) * 64 + lane;                                            \
      int r = p >> 3, c = p & 7;                                                    \
      int cs = c ^ (r & 7);                                                         \
      int rc = CLAMP_B;                                                             \
      const unsigned short* g = Bm + (size_t)(bcol + rc) * K + k0 + cs * 8;         \
      __builtin_amdgcn_global_load_lds(                                             \
        (const __attribute__((address_space(1))) unsigned int*)g,                   \
        (__attribute__((address_space(3))) unsigned int*)(tB + (size_t)(i * 8 + wid) * 64 * 8), \
        16, 0, 0);                                                                  \
    }                                                                               \
    __syncthreads();                                                                \
    _Pragma("unroll")                                                               \
    for (int kk = 0; kk < 2; kk++){                                                 \
      short8 av[4], bv[4];                                                          \
      _Pragma("unroll")                                                             \
      for (int m = 0; m < 4; m++){                                                  \
        int R = wr * 64 + m * 16 + lr;                                              \
        int c = kk * 4 + lk;                                                        \
        av[m] = *(const short8*)&tA[R * 64 + ((c ^ (R & 7)) << 3)];                 \
      }                                                                             \
      _Pragma("unroll")                                                             \
      for (int n = 0; n < 4; n++){                                                  \
        int R = wc * 64 + n * 16 + lr;                                              \
        int c = kk * 4 + lk;                                                        \
        bv[n] = *(const short8*)&tB[R * 64 + ((c ^ (R & 7)) << 3)];                 \
      }                                                                             \
      _Pragma("unroll")                                                             \
      for (int m = 0; m < 4; m++)                                                   \
        _Pragma("unroll")                                                           \
        for (int n = 0; n < 4; n++)                                                 \
          acc[m][n] = __builtin_amdgcn_mfma_f32_16x16x32_bf16(av[m], bv[n], acc[m][n], 0, 0, 0); \
    }                                                                               \
    __syncthreads();                                                                \
  }

// ---------------- fc GEMM: 256x128, bias+GELU(fast tanh) -> bf16 ----------------
__global__ __launch_bounds__(512) void gemm_fc256(
    const unsigned short* __restrict__ A,
    const unsigned short* __restrict__ Bm,
    const float* __restrict__ bias,
    unsigned short* __restrict__ outB,
    int M, int N, int K)
{
  __shared__ unsigned short tA[16384];
  __shared__ unsigned short tB[8192];
  const int lane = threadIdx.x & 63;
  const int wid  = threadIdx.x >> 6;
  const int wr = wid >> 1, wc = wid & 1;
  const int lr = lane & 15, lk = lane >> 4;
  const int nbx = gridDim.x, nby = gridDim.y;
  const int nwg = nbx * nby;
  const int lin = blockIdx.y * nbx + blockIdx.x;
  const int qq = nwg >> 3, rr8 = nwg & 7;
  const int xcd = lin & 7, loc = lin >> 3;
  const int wg = (xcd < rr8 ? xcd * (qq + 1) : rr8 * (qq + 1) + (xcd - rr8) * qq) + loc;
  const int mblk = wg / nbx, nblk = wg % nbx;
  const int brow = mblk * 256;
  const int bcol = nblk * 128;

  GEMM256_MAIN_LOOP(r)

  #pragma unroll
  for (int m = 0; m < 4; m++){
    #pragma unroll
    for (int n = 0; n < 4; n++){
      int col = bcol + wc * 64 + n * 16 + lr;
      float bco = bias[col];
      #pragma unroll
      for (int j = 0; j < 4; j++){
        int row = brow + wr * 64 + m * 16 + lk * 4 + j;
        float v = acc[m][n][j] + bco;
        float z = 0.79788456080286536f * (v + 0.044715f * v * v * v);
        float az = fabsf(z);
        float e = __expf(-2.f * az);
        float t = (1.f - e) / (1.f + e);
        t = z < 0.f ? -t : t;
        v = 0.5f * v * (1.f + t);
        outB[(size_t)row * N + col] = f2bf(v);
      }
    }
  }
}

// ---------------- QKV GEMM 256x128 with fused repack ----------------
__global__ __launch_bounds__(512) void gemm_qkv256(
    const unsigned short* __restrict__ A,
    const unsigned short* __restrict__ Bm,
    const float* __restrict__ bias,
    unsigned short* __restrict__ Qb,   // [BH,1024,64]
    unsigned short* __restrict__ Kb,
    unsigned short* __restrict__ VT,   // [BH,64,1024]
    int M, int N, int K)
{
  __shared__ unsigned short tA[16384];
  __shared__ unsigned short tB[8192];
  const int lane = threadIdx.x & 63;
  const int wid  = threadIdx.x >> 6;
  const int wr = wid >> 1, wc = wid & 1;
  const int lr = lane & 15, lk = lane >> 4;
  const int nbx = gridDim.x, nby = gridDim.y;
  const int nwg = nbx * nby;
  const int lin = blockIdx.y * nbx + blockIdx.x;
  const int qq = nwg >> 3, rr8 = nwg & 7;
  const int xcd = lin & 7, loc = lin >> 3;
  const int wg = (xcd < rr8 ? xcd * (qq + 1) : rr8 * (qq + 1) + (xcd - rr8) * qq) + loc;
  const int mblk = wg / nbx, nblk = wg % nbx;
  const int brow = mblk * 256;         // never spans a 1024-row batch boundary
  const int bcol = nblk * 128;

  GEMM256_MAIN_LOOP(r)

  const int b = brow >> 10, tstart = brow & 1023;
  if (bcol < 1536){
    // Q or K scatter: [BH, t, 64] bf16
    #pragma unroll
    for (int m = 0; m < 4; m++)
      #pragma unroll
      for (int n = 0; n < 4; n++){
        int col = bcol + wc * 64 + n * 16 + lr;
        float bco = bias[col];
        int isK = col >= 768;
        int h = (isK ? col - 768 : col) >> 6;
        unsigned short* dstp = isK ? Kb : Qb;
        #pragma unroll
        for (int j = 0; j < 4; j++){
          int t = tstart + wr * 64 + m * 16 + lk * 4 + j;
          dstp[(((size_t)b * 12 + h) * 1024 + t) * 64 + (col & 63)] =
              f2bf(acc[m][n][j] + bco);
        }
      }
  } else {
    // V: transpose 256x128 in four 64-row passes through 64x136 LDS (in tA)
    unsigned short* sh = tA;   // 8704 shorts used
    const int h0 = (bcol - 1536) >> 6;
    #pragma unroll
    for (int half = 0; half < 4; half++){
      __syncthreads();
      if (wr == half){
        #pragma unroll
        for (int m = 0; m < 4; m++)
          #pragma unroll
          for (int n = 0; n < 4; n++){
            int lcol = wc * 64 + n * 16 + lr;
            float bco = bias[bcol + lcol];
            #pragma unroll
            for (int j = 0; j < 4; j++)
              sh[(m * 16 + lk * 4 + j) * 136 + lcol] = f2bf(acc[m][n][j] + bco);
          }
      }
      __syncthreads();
      int c_local = threadIdx.x & 127, tpart = threadIdx.x >> 7; // 0..3 (16 rows each)
      int h = h0 + (c_local >> 6);
      int d = c_local & 63;
      unsigned short* vrow = VT + (((size_t)b * 12 + h) * 64 + d) * 1024
                           + tstart + half * 64 + tpart * 16;
      #pragma unroll
      for (int i = 0; i < 2; i++){
        short8 pk;
        #pragma unroll
        for (int s2 = 0; s2 < 8; s2++)
          pk[s2] = (short)sh[(tpart * 16 + i * 8 + s2) * 136 + c_local];
        *(short8*)&vrow[i * 8] = pk;
      }
    }
  }
}

// ---------------- small-N GEMM: BM=128 x BN=64, 4 waves (2Mx2N, wave 64x32) ----------------
__global__ __launch_bounds__(256) void gemm_n64(
    const unsigned short* __restrict__ A,
    const unsigned short* __restrict__ Bm,
    const float* __restrict__ bias,
    const float* __restrict__ resid,
    float* __restrict__ outF,
    int M, int N, int K)
{
  __shared__ unsigned short tA[8192];   // 128 x 64
  __shared__ unsigned short tB[4096];   // 64 x 64
  const int lane = threadIdx.x & 63;
  const int wid  = threadIdx.x >> 6;
  const int wr = wid >> 1, wc = wid & 1;
  const int lr = lane & 15, lk = lane >> 4;
  const int nbx = gridDim.x, nby = gridDim.y;   // nbx = N/64
  const int nwg = nbx * nby;
  const int lin = blockIdx.y * nbx + blockIdx.x;
  const int qq = nwg >> 3, rr8 = nwg & 7;
  const int xcd = lin & 7, loc = lin >> 3;
  const int wg = (xcd < rr8 ? xcd * (qq + 1) : rr8 * (qq + 1) + (xcd - rr8) * qq) + loc;
  const int mblk = wg / nbx, nblk = wg % nbx;
  const int brow = mblk * 128;
  const int bcol = nblk * 64;

  f32x4 acc[4][2];
  #pragma unroll
  for (int m = 0; m < 4; m++)
    #pragma unroll
    for (int n = 0; n < 2; n++)
      acc[m][n] = (f32x4){0.f, 0.f, 0.f, 0.f};

  for (int k0 = 0; k0 < K; k0 += 64){
    #pragma unroll
    for (int i = 0; i < 4; i++){
      int p = (i * 4 + wid) * 64 + lane;      // A: 1024 chunks
      int r = p >> 3, c = p & 7;
      int cs = c ^ (r & 7);
      const unsigned short* g = A + (size_t)(brow + r) * K + k0 + cs * 8;
      __builtin_amdgcn_global_load_lds(
        (const __attribute__((address_space(1))) unsigned int*)g,
        (__attribute__((address_space(3))) unsigned int*)(tA + (size_t)(i * 4 + wid) * 64 * 8),
        16, 0, 0);
    }
    #pragma unroll
    for (int i = 0; i < 2; i++){
      int p = (i * 4 + wid) * 64 + lane;      // B: 512 chunks (64 rows)
      int r = p >> 3, c = p & 7;
      int cs = c ^ (r & 7);
      const unsigned short* g = Bm + (size_t)(bcol + r) * K + k0 + cs * 8;
      __builtin_amdgcn_global_load_lds(
        (const __attribute__((address_space(1))) unsigned int*)g,
        (__attribute__((address_space(3))) unsigned int*)(tB + (size_t)(i * 4 + wid) * 64 * 8),
        16, 0, 0);
    }
    __syncthreads();
    #pragma unroll
    for (int kk = 0; kk < 2; kk++){
      short8 av[4], bv[2];
      #pragma unroll
      for (int m = 0; m < 4; m++){
        int R = wr * 64 + m * 16 + lr;
        int c = kk * 4 + lk;
        av[m] = *(const short8*)&tA[R * 64 + ((c ^ (R & 7)) << 3)];
      }
      #pragma unroll
      for (int n = 0; n < 2; n++){
        int R = wc * 32 + n * 16 + lr;
        int c = kk * 4 + lk;
        bv[n] = *(const short8*)&tB[R * 64 + ((c ^ (R & 7)) << 3)];
      }
      #pragma unroll
      for (int m = 0; m < 4; m++)
        #pragma unroll
        for (int n = 0; n < 2; n++)
          acc[m][n] = __builtin_amdgcn_mfma_f32_16x16x32_bf16(av[m], bv[n], acc[m][n], 0, 0, 0);
    }
    __syncthreads();
  }

  #pragma unroll
  for (int m = 0; m < 4; m++){
    #pragma unroll
    for (int n = 0; n < 2; n++){
      int col = bcol + wc * 32 + n * 16 + lr;
      float bco = bias[col];
      #pragma unroll
      for (int j = 0; j < 4; j++){
        int row = brow + wr * 64 + m * 16 + lk * 4 + j;
        float v = acc[m][n][j] + bco + resid[(size_t)row * N + col];
        outF[(size_t)row * N + col] = v;
      }
    }
  }
}

// ---------------- tiny-tile GEMM: BM=64 x BN=64, 4 waves (2Mx2N, wave 32x32) ----------------
__global__ __launch_bounds__(256) void gemm_n64s(
    const unsigned short* __restrict__ A,
    const unsigned short* __restrict__ Bm,
    const float* __restrict__ bias,
    const float* __restrict__ resid,
    float* __restrict__ outF,
    int M, int N, int K)
{
  __shared__ unsigned short tA[4096];   // 64 x 64
  __shared__ unsigned short tB[4096];   // 64 x 64
  const int lane = threadIdx.x & 63;
  const int wid  = threadIdx.x >> 6;
  const int wr = wid >> 1, wc = wid & 1;
  const int lr = lane & 15, lk = lane >> 4;
  const int nbx = gridDim.x, nby = gridDim.y;   // nbx = N/64, nby = M/64
  const int nwg = nbx * nby;
  const int lin = blockIdx.y * nbx + blockIdx.x;
  const int qq = nwg >> 3, rr8 = nwg & 7;
  const int xcd = lin & 7, loc = lin >> 3;
  const int wg = (xcd < rr8 ? xcd * (qq + 1) : rr8 * (qq + 1) + (xcd - rr8) * qq) + loc;
  const int mblk = wg / nbx, nblk = wg % nbx;
  const int brow = mblk * 64;
  const int bcol = nblk * 64;

  f32x4 acc[2][2];
  #pragma unroll
  for (int m = 0; m < 2; m++)
    #pragma unroll
    for (int n = 0; n < 2; n++)
      acc[m][n] = (f32x4){0.f, 0.f, 0.f, 0.f};

  for (int k0 = 0; k0 < K; k0 += 64){
    #pragma unroll
    for (int i = 0; i < 2; i++){
      int p = (i * 4 + wid) * 64 + lane;      // 512 chunks each
      int r = p >> 3, c = p & 7;
      int cs = c ^ (r & 7);
      const unsigned short* ga = A + (size_t)(brow + r) * K + k0 + cs * 8;
      __builtin_amdgcn_global_load_lds(
        (const __attribute__((address_space(1))) unsigned int*)ga,
        (__attribute__((address_space(3))) unsigned int*)(tA + (size_t)(i * 4 + wid) * 64 * 8),
        16, 0, 0);
      const unsigned short* gb = Bm + (size_t)(bcol + r) * K + k0 + cs * 8;
      __builtin_amdgcn_global_load_lds(
        (const __attribute__((address_space(1))) unsigned int*)gb,
        (__attribute__((address_space(3))) unsigned int*)(tB + (size_t)(i * 4 + wid) * 64 * 8),
        16, 0, 0);
    }
    __syncthreads();
    #pragma unroll
    for (int kk = 0; kk < 2; kk++){
      short8 av[2], bv[2];
      #pragma unroll
      for (int m = 0; m < 2; m++){
        int R = wr * 32 + m * 16 + lr;
        int c = kk * 4 + lk;
        av[m] = *(const short8*)&tA[R * 64 + ((c ^ (R & 7)) << 3)];
      }
      #pragma unroll
      for (int n = 0; n < 2; n++){
        int R = wc * 32 + n * 16 + lr;
        int c = kk * 4 + lk;
        bv[n] = *(const short8*)&tB[R * 64 + ((c ^ (R & 7)) << 3)];
      }
      #pragma unroll
      for (int m = 0; m < 2; m++)
        #pragma unroll
        for (int n = 0; n < 2; n++)
          acc[m][n] = __builtin_amdgcn_mfma_f32_16x16x32_bf16(av[m], bv[n], acc[m][n], 0, 0, 0);
    }
    __syncthreads();
  }

  #pragma unroll
  for (int m = 0; m < 2; m++){
    #pragma unroll
    for (int n = 0; n < 2; n++){
      int col = bcol + wc * 32 + n * 16 + lr;
      float bco = bias[col];
      #pragma unroll
      for (int j = 0; j < 4; j++){
        int row = brow + wr * 32 + m * 16 + lk * 4 + j;
        float v = acc[m][n][j] + bco + resid[(size_t)row * N + col];
        outF[(size_t)row * N + col] = v;
      }
    }
  }
}

// ---------------- lm_head GEMM: BM=256 x BN=128, 512 threads (8 waves 4Mx2N) ----------------
__global__ __launch_bounds__(512) void gemm_head(
    const unsigned short* __restrict__ A,
    const unsigned short* __restrict__ Bm,
    float* __restrict__ outF,
    float2* __restrict__ lossPart,
    int M, int N, int K, int nPart)
{
  __shared__ unsigned short tA[16384];   // 256 x 64
  __shared__ unsigned short tB[8192];    // 128 x 64
  const int lane = threadIdx.x & 63;
  const int wid  = threadIdx.x >> 6;     // 0..7
  const int wr = wid >> 1, wc = wid & 1; // wr 0..3, wc 0..1
  const int lr = lane & 15, lk = lane >> 4;
  const int nblk = blockIdx.x, mblk = blockIdx.y;  // plain N-fastest
  const int brow = mblk * 256;
  const int bcol = nblk * 128;
  const int nValid = N - bcol;

  GEMM256_MAIN_LOOP(r < nValid ? r : (nValid - 1))

  #pragma unroll
  for (int m = 0; m < 4; m++){
    #pragma unroll
    for (int n = 0; n < 4; n++){
      int col = bcol + wc * 64 + n * 16 + lr;
      if (col < N){
        #pragma unroll
        for (int j = 0; j < 4; j++){
          int row = brow + wr * 64 + m * 16 + lk * 4 + j;
          outF[(size_t)row * N + col] = acc[m][n][j];
        }
      }
    }
  }

  // fused loss partials: per row (max, sum_exp) over this 128-col slice
  float* mred = (float*)tA;          // 512+512 floats, safe after final barrier
  float* sred = mred + 512;
  #pragma unroll
  for (int m = 0; m < 4; m++){
    #pragma unroll
    for (int j = 0; j < 4; j++){
      float vv[4];
      float mx = -3.4e38f;
      #pragma unroll
      for (int n = 0; n < 4; n++){
        int col = bcol + wc * 64 + n * 16 + lr;
        vv[n] = (col < N) ? acc[m][n][j] : -3.4e38f;
        mx = fmaxf(mx, vv[n]);
      }
      #pragma unroll
      for (int msk = 1; msk < 16; msk <<= 1)
        mx = fmaxf(mx, __shfl_xor(mx, msk, 64));
      float sm = 0.f;
      #pragma unroll
      for (int n = 0; n < 4; n++){
        int col = bcol + wc * 64 + n * 16 + lr;
        if (col < N) sm += __expf(vv[n] - mx);
      }
      #pragma unroll
      for (int msk = 1; msk < 16; msk <<= 1)
        sm += __shfl_xor(sm, msk, 64);
      if (lr == 0){
        int rid = (wr * 2 + wc) * 64 + m * 16 + lk * 4 + j;   // [0,512)
        mred[rid] = mx; sred[rid] = sm;
      }
    }
  }
  __syncthreads();
  if (threadIdx.x < 256){
    int wrq = threadIdx.x >> 6, rowi = threadIdx.x & 63;       // wrq 0..3
    float m0 = mred[(wrq * 2 + 0) * 64 + rowi];
    float m1 = mred[(wrq * 2 + 1) * 64 + rowi];
    float s0 = sred[(wrq * 2 + 0) * 64 + rowi];
    float s1 = sred[(wrq * 2 + 1) * 64 + rowi];
    float Mv = fmaxf(m0, m1);
    float Sv = (s0 > 0.f ? s0 * __expf(m0 - Mv) : 0.f)
             + (s1 > 0.f ? s1 * __expf(m1 - Mv) : 0.f);
    int grow = brow + wrq * 64 + rowi;
    lossPart[(size_t)grow * nPart + nblk] = make_float2(Mv, Sv);
  }
}

// ---------------- MFMA flash attention: QBLK=64, 4 waves, 2 kt-tiles per stage round ----------------
// Barriers: 1 per kt-tile (was 3). The P buffer is per-wave, so the write->read
// ordering is in-wave (compiler lgkmcnt); K/V buffers are written only before the
// round barrier and read only after it.
__global__ __launch_bounds__(256) void attn_mfma(
    const unsigned short* __restrict__ Qb,   // [BH,1024,64]
    const unsigned short* __restrict__ Kb,   // [BH,1024,64]
    const unsigned short* __restrict__ VT,   // [BH,64,1024]
    unsigned short* __restrict__ y)          // [B*T,768]
{
  __shared__ unsigned short Kl[2][64 * 64];
  __shared__ unsigned short Vl[2][64 * 64];
  __shared__ unsigned short Pl[4][16 * 72];
  const int xq = blockIdx.x;
  const int qt = (xq & 1) ? (xq >> 1) : (15 - (xq >> 1)); // interleave heavy/light
  const int h = blockIdx.y, b = blockIdx.z;
  const size_t bh = (size_t)(b * 12 + h);
  const int lane = threadIdx.x & 63;
  const int w = threadIdx.x >> 6;
  const int lr = lane & 15, lk = lane >> 4;

  short8 aq[2];
  {
    const unsigned short* qrow = Qb + ((bh * 1024) + qt * 64 + w * 16 + lr) * 64;
    aq[0] = *(const short8*)&qrow[lk * 8];
    aq[1] = *(const short8*)&qrow[32 + lk * 8];
  }

  f32x4 o[4];
  #pragma unroll
  for (int n = 0; n < 4; n++) o[n] = (f32x4){0.f, 0.f, 0.f, 0.f};
  float mold[4] = {-1e30f, -1e30f, -1e30f, -1e30f};
  float lsum[4] = {0.f, 0.f, 0.f, 0.f};

  for (int kt0 = 0; kt0 <= qt; kt0 += 2){
    // stage up to 2 kt-tiles (K + VT each), 64x64 swizzled buffers
    #pragma unroll
    for (int u = 0; u < 2; u++){
      int kt = kt0 + u;
      if (kt <= qt){
        #pragma unroll
        for (int i = 0; i < 2; i++){
          int p = (i * 4 + w) * 64 + lane;
          int r = p >> 3, c = p & 7;
          int cs = c ^ (r & 7);
          const unsigned short* gk = Kb + (bh * 1024 + (size_t)kt * 64 + r) * 64 + cs * 8;
          __builtin_amdgcn_global_load_lds(
            (const __attribute__((address_space(1))) unsigned int*)gk,
            (__attribute__((address_space(3))) unsigned int*)(Kl[u] + (size_t)(i * 4 + w) * 64 * 8),
            16, 0, 0);
          const unsigned short* gv = VT + (bh * 64 + r) * 1024 + (size_t)kt * 64 + cs * 8;
          __builtin_amdgcn_global_load_lds(
            (const __attribute__((address_space(1))) unsigned int*)gv,
            (__attribute__((address_space(3))) unsigned int*)(Vl[u] + (size_t)(i * 4 + w) * 64 * 8),
            16, 0, 0);
        }
      }
    }
    __syncthreads();

    #pragma unroll
    for (int u = 0; u < 2; u++){
      int kt = kt0 + u;
      if (kt <= qt){
        f32x4 s[4];
        #pragma unroll
        for (int n = 0; n < 4; n++) s[n] = (f32x4){0.f, 0.f, 0.f, 0.f};
        __builtin_amdgcn_s_setprio(1);
        #pragma unroll
        for (int ck = 0; ck < 2; ck++){
          #pragma unroll
          for (int n = 0; n < 4; n++){
            int R = n * 16 + lr, c = ck * 4 + lk;
            short8 bv = *(const short8*)&Kl[u][R * 64 + ((c ^ (R & 7)) << 3)];
            s[n] = __builtin_amdgcn_mfma_f32_16x16x32_bf16(aq[ck], bv, s[n], 0, 0, 0);
          }
        }
        __builtin_amdgcn_s_setprio(0);
        #pragma unroll
        for (int n = 0; n < 4; n++)
          #pragma unroll
          for (int j = 0; j < 4; j++){
            float v = s[n][j] * 0.125f;
            if (kt == qt && (n * 16 + lr) > (w * 16 + lk * 4 + j)) v = -1e30f;
            s[n][j] = v;
          }
        float mt[4];
        #pragma unroll
        for (int j = 0; j < 4; j++)
          mt[j] = fmaxf(fmaxf(s[0][j], s[1][j]), fmaxf(s[2][j], s[3][j]));
        #pragma unroll
        for (int msk = 1; msk < 16; msk <<= 1)
          #pragma unroll
          for (int j = 0; j < 4; j++)
            mt[j] = fmaxf(mt[j], __shfl_xor(mt[j], msk, 64));
        #pragma unroll
        for (int j = 0; j < 4; j++){
          float mn = fmaxf(mold[j], mt[j]);
          float a = __expf(mold[j] - mn);
          mold[j] = mn;
          lsum[j] *= a;
          #pragma unroll
          for (int n = 0; n < 4; n++){
            float p = __expf(s[n][j] - mn);
            s[n][j] = p;
            lsum[j] += p;
          }
          #pragma unroll
          for (int n2 = 0; n2 < 4; n2++) o[n2][j] *= a;
        }
        // P to per-wave LDS (no barrier: in-wave ds ordering via lgkmcnt)
        #pragma unroll
        for (int n = 0; n < 4; n++)
          #pragma unroll
          for (int j = 0; j < 4; j++)
            Pl[w][(lk * 4 + j) * 72 + n * 16 + lr] = f2bf(s[n][j]);
        __builtin_amdgcn_s_setprio(1);
        #pragma unroll
        for (int ck = 0; ck < 2; ck++){
          short8 pa = *(const short8*)&Pl[w][lr * 72 + ck * 32 + lk * 8];
          #pragma unroll
          for (int n2 = 0; n2 < 4; n2++){
            int R = n2 * 16 + lr, c = ck * 4 + lk;
            short8 vv = *(const short8*)&Vl[u][R * 64 + ((c ^ (R & 7)) << 3)];
            o[n2] = __builtin_amdgcn_mfma_f32_16x16x32_bf16(pa, vv, o[n2], 0, 0, 0);
          }
        }
        __builtin_amdgcn_s_setprio(0);
      }
    }
    __syncthreads();   // protect Kl/Vl before next round's staging
  }

  #pragma unroll
  for (int msk = 1; msk < 16; msk <<= 1)
    #pragma unroll
    for (int j = 0; j < 4; j++)
      lsum[j] += __shfl_xor(lsum[j], msk, 64);
  float inv[4];
  #pragma unroll
  for (int j = 0; j < 4; j++) inv[j] = 1.f / lsum[j];

  #pragma unroll
  for (int n2 = 0; n2 < 4; n2++)
    #pragma unroll
    for (int j = 0; j < 4; j++){
      size_t row = (size_t)(b * 1024 + qt * 64 + w * 16 + lk * 4 + j);
      y[row * 768 + h * 64 + n2 * 16 + lr] = f2bf(o[n2][j] * inv[j]);
    }
}

// ---------------- loss: combine per-block partials ----------------
__global__ __launch_bounds__(64) void loss_rows2(const float2* __restrict__ part,
    const float* __restrict__ logits, const int* __restrict__ targets,
    float* __restrict__ nll, int nPart){
  int row = blockIdx.x, lane = threadIdx.x;
  float m = -3.4e38f, s = 0.f;
  for (int i = lane; i < nPart; i += 64){
    float2 p = part[(size_t)row * nPart + i];
    if (p.y > 0.f){
      float nm = fmaxf(m, p.x);
      s = s * __expf(m - nm) + p.y * __expf(p.x - nm);
      m = nm;
    }
  }
  #pragma unroll
  for (int o = 32; o; o >>= 1){
    float m2 = __shfl_xor(m, o, 64);
    float s2 = __shfl_xor(s, o, 64);
    float nm = fmaxf(m, m2);
    s = s * __expf(m - nm) + s2 * __expf(m2 - nm);
    m = nm;
  }
  if (lane == 0)
    nll[row] = m + logf(s) - logits[(size_t)row * VOC + targets[row]];
}

__global__ __launch_bounds__(256) void loss_final(const float* __restrict__ nll,
                                                  float* __restrict__ out){
  __shared__ float red[4];
  int tid = threadIdx.x;
  float s = 0.f;
  for (int i = tid; i < 4096; i += 256) s += nll[i];
  #pragma unroll
  for (int o = 32; o; o >>= 1) s += __shfl_xor(s, o, 64);
  if ((tid & 63) == 0) red[tid >> 6] = s;
  __syncthreads();
  if (tid == 0) out[0] = (red[0] + red[1] + red[2] + red[3]) * (1.f / 4096.f);
}

// ---------------- host ----------------
extern "C" void kernel_launch(void* const* d_in, const int* in_sizes, int n_in,
                              void* d_out, int out_size, void* d_ws, size_t ws_size,
                              hipStream_t stream){
  (void)in_sizes; (void)n_in; (void)out_size;
  const int*   idx     = (const int*)d_in[0];
  const int*   targets = (const int*)d_in[1];
  const float* wte     = (const float*)d_in[2];
  const float* wpe     = (const float*)d_in[3];
  const float* ln1w    = (const float*)d_in[4];
  const float* ln1b    = (const float*)d_in[5];
  const float* qkvw    = (const float*)d_in[6];
  const float* qkvb    = (const float*)d_in[7];
  const float* apw     = (const float*)d_in[8];
  const float* apb     = (const float*)d_in[9];
  const float* ln2w    = (const float*)d_in[10];
  const float* ln2b    = (const float*)d_in[11];
  const float* fcw     = (const float*)d_in[12];
  const float* fcb     = (const float*)d_in[13];
  const float* mpw     = (const float*)d_in[14];
  const float* mpb     = (const float*)d_in[15];
  const float* lnfw    = (const float*)d_in[16];
  const float* lnfb    = (const float*)d_in[17];

  char* ws = (char*)d_ws;
  size_t off = 0;
  auto alloc = [&](size_t bytes){
    void* p = ws + off; off += (bytes + 255) & ~(size_t)255; return p;
  };
  float* x               = (float*)alloc((size_t)4096 * 768 * 4);
  unsigned short* hbf    = (unsigned short*)alloc((size_t)4096 * 768 * 2);
  unsigned short* ybf    = (unsigned short*)alloc((size_t)4096 * 768 * 2);
  unsigned short* gbf    = (unsigned short*)alloc((size_t)4096 * 3072 * 2);
  unsigned short* wtebf  = (unsigned short*)alloc((size_t)VOC * 768 * 2);
  unsigned short* qb     = (unsigned short*)alloc((size_t)48 * 1024 * 64 * 2);
  unsigned short* kbf    = (unsigned short*)alloc((size_t)48 * 1024 * 64 * 2);
  unsigned short* vtb    = (unsigned short*)alloc((size_t)48 * 1024 * 64 * 2);
  float2* lossPart       = (float2*)alloc((size_t)4096 * 393 * 8);
  float* nll             = (float*)alloc((size_t)4096 * 4);
  // transposed weights: all 12 layers if ws allows, else per-layer ping buffer
  bool mega = (ws_size - off) >= (12 * LSTR * 2 + 256);
  unsigned short* wTall = (unsigned short*)alloc(mega ? 12 * LSTR * 2 : LSTR * 2);

  float* logits  = (float*)d_out;
  float* lossOut = logits + (size_t)4096 * VOC;

  cvt_bf16_kernel<<<2048, 256, 0, stream>>>(wte, wtebf, (VOC * 768) / 4);
  embed_kernel<<<4096, 192, 0, stream>>>(idx, wte, wpe, x);
  if (mega)
    transpose_all<<<dim3(6912, 12), dim3(32, 8), 0, stream>>>(qkvw, apw, fcw, mpw, wTall);

  for (int l = 0; l < 12; l++){
    unsigned short* wTl = wTall;
    if (mega) wTl = wTall + (size_t)l * LSTR;
    else
      transpose_all<<<dim3(6912, 1), dim3(32, 8), 0, stream>>>(
          qkvw + (size_t)l * 768 * 2304, apw + (size_t)l * 768 * 768,
          fcw + (size_t)l * 768 * 3072, mpw + (size_t)l * 3072 * 768, wTall);

    ln_kernel<<<1024, 256, 0, stream>>>(x, ln1w + l * 768, ln1b + l * 768, hbf);
    gemm_qkv256<<<dim3(2304 / 128, 4096 / 256), 512, 0, stream>>>(
        hbf, wTl + QKV_T_OFF, qkvb + l * 2304, qb, kbf, vtb, 4096, 2304, 768);
    attn_mfma<<<dim3(16, 12, 4), 256, 0, stream>>>(qb, kbf, vtb, ybf);
    gemm_n64s<<<dim3(768 / 64, 4096 / 64), 256, 0, stream>>>(
        ybf, wTl + AP_T_OFF, apb + l * 768, x, x, 4096, 768, 768);
    ln_kernel<<<1024, 256, 0, stream>>>(x, ln2w + l * 768, ln2b + l * 768, hbf);
    gemm_fc256<<<dim3(3072 / 128, 4096 / 256), 512, 0, stream>>>(
        hbf, wTl + FC_T_OFF, fcb + l * 3072, gbf, 4096, 3072, 768);
    gemm_n64<<<dim3(768 / 64, 4096 / 128), 256, 0, stream>>>(
        gbf, wTl + MP_T_OFF, mpb + l * 768, x, x, 4096, 768, 3072);
  }
  ln_kernel<<<1024, 256, 0, stream>>>(x, lnfw, lnfb, hbf);
  gemm_head<<<dim3((VOC + 127) / 128, 4096 / 256), 512, 0, stream>>>(
      hbf, wtebf, logits, lossPart, 4096, VOC, 768, (VOC + 127) / 128);
  loss_rows2<<<4096, 64, 0, stream>>>(lossPart, logits, targets, nll, (VOC + 127) / 128);
  loss_final<<<1, 256, 0, stream>>>(nll, lossOut);
}